// Round 1
// baseline (937.092 us; speedup 1.0000x reference)
//
#include <hip/hip_runtime.h>
#include <cstdint>
#include <cstddef>

// ---------------- CSR build ----------------

__global__ void edge_count_deg(const int* __restrict__ row, const float* __restrict__ w,
                               float* __restrict__ deg, int* __restrict__ cnt, int E) {
    int e = blockIdx.x * blockDim.x + threadIdx.x;
    if (e < E) {
        int r = row[e];
        atomicAdd(&deg[r], w[e]);
        atomicAdd(&cnt[r], 1);
    }
}

__global__ void make_dinv(float* __restrict__ deg, int n) {
    int i = blockIdx.x * blockDim.x + threadIdx.x;
    if (i < n) {
        float d = deg[i];
        deg[i] = d > 0.f ? 1.f / sqrtf(d) : 0.f;
    }
}

// exclusive scan over n ints: per-block (1024 elems) scan + partials
__global__ void scan_block(const int* __restrict__ in, int* __restrict__ out,
                           int* __restrict__ part, int n) {
    __shared__ int sh[256];
    int tid = threadIdx.x;
    int base = blockIdx.x * 1024 + tid * 4;
    int v[4];
#pragma unroll
    for (int j = 0; j < 4; ++j) v[j] = (base + j < n) ? in[base + j] : 0;
    int s = v[0] + v[1] + v[2] + v[3];
    sh[tid] = s;
    __syncthreads();
    for (int off = 1; off < 256; off <<= 1) {
        int t = (tid >= off) ? sh[tid - off] : 0;
        __syncthreads();
        sh[tid] += t;
        __syncthreads();
    }
    int run = sh[tid] - s;  // exclusive prefix for this thread
#pragma unroll
    for (int j = 0; j < 4; ++j) {
        if (base + j < n) out[base + j] = run;
        run += v[j];
    }
    if (tid == 255) part[blockIdx.x] = sh[255];
}

__global__ void scan_part_k(int* __restrict__ part, int nb) {
    __shared__ int sh[256];
    int tid = threadIdx.x;
    int v = (tid < nb) ? part[tid] : 0;
    sh[tid] = v;
    __syncthreads();
    for (int off = 1; off < 256; off <<= 1) {
        int t = (tid >= off) ? sh[tid - off] : 0;
        __syncthreads();
        sh[tid] += t;
        __syncthreads();
    }
    if (tid < nb) part[tid] = sh[tid] - v;
}

__global__ void scan_add(int* __restrict__ out, const int* __restrict__ part, int n) {
    int i = blockIdx.x * blockDim.x + threadIdx.x;
    if (i < n) out[i] += part[i >> 10];
}

__global__ void copy_int(const int* __restrict__ a, int* __restrict__ b, int n) {
    int i = blockIdx.x * blockDim.x + threadIdx.x;
    if (i < n) b[i] = a[i];
}

__global__ void edge_fill(const int* __restrict__ row, const int* __restrict__ col,
                          const float* __restrict__ w, const float* __restrict__ dinv,
                          int* __restrict__ cursor, int* __restrict__ ci,
                          float* __restrict__ ev, int E) {
    int e = blockIdx.x * blockDim.x + threadIdx.x;
    if (e < E) {
        int r = row[e], c = col[e];
        int idx = atomicAdd(&cursor[r], 1);
        ci[idx] = c;
        ev[idx] = -dinv[r] * w[e] * dinv[c];
    }
}

// ---------------- SpMM (CSR) ----------------
// y[r][:] = sum_e norm[e] * x[col[e]][:]        (AXPBY=false)
// y[r][:] = 2*sum_e norm[e] * x[col[e]][:] - z[r][:]   (AXPBY=true)
template <int F, bool AXPBY>
__global__ __launch_bounds__(256) void spmm_csr(const int* __restrict__ rp,
                                                const int* __restrict__ ci,
                                                const float* __restrict__ ev,
                                                const float* __restrict__ x,
                                                const float* __restrict__ z,
                                                float* __restrict__ y, int n) {
    constexpr int TPR = F / 4;                 // threads per row (float4 each)
    constexpr int RPB = 256 / TPR;             // rows per block
    int r = blockIdx.x * RPB + threadIdx.x / TPR;
    if (r >= n) return;
    int f = (threadIdx.x % TPR) * 4;
    int e0 = rp[r], e1 = rp[r + 1];
    float4 acc = make_float4(0.f, 0.f, 0.f, 0.f);
    for (int e = e0; e < e1; ++e) {
        float w = ev[e];
        int c = ci[e];
        const float4 xv = *reinterpret_cast<const float4*>(x + (size_t)c * F + f);
        acc.x += w * xv.x;
        acc.y += w * xv.y;
        acc.z += w * xv.z;
        acc.w += w * xv.w;
    }
    if (AXPBY) {
        const float4 zv = *reinterpret_cast<const float4*>(z + (size_t)r * F + f);
        acc.x = 2.f * acc.x - zv.x;
        acc.y = 2.f * acc.y - zv.y;
        acc.z = 2.f * acc.z - zv.z;
        acc.w = 2.f * acc.w - zv.w;
    }
    *reinterpret_cast<float4*>(y + (size_t)r * F + f) = acc;
}

// ---------------- 3-operand GEMM ----------------
// out[n][64] = act( A0@W[0:F] + A1@W[F:2F] + A2@W[2F:3F] + bias )
// W is contiguous [3F][64] row-major (exactly the (3,F,64) input layout).
template <int F, bool RELU>
__global__ __launch_bounds__(256) void gemm3(const float* __restrict__ A0,
                                             const float* __restrict__ A1,
                                             const float* __restrict__ A2,
                                             const float* __restrict__ W,
                                             const float* __restrict__ bias,
                                             float* __restrict__ out, int n) {
    __shared__ float As[64][33];
    __shared__ float Bs[32][64];
    const float* Aptr[3] = {A0, A1, A2};
    int tid = threadIdx.x;
    int r0 = blockIdx.x * 64;
    int tx = tid & 15, ty = tid >> 4;  // 16x16 threads, 4x4 micro-tile
    float c[4][4] = {};

    constexpr int KT = 3 * F / 32;
    for (int kt = 0; kt < KT; ++kt) {
        int k0 = kt * 32;
        const float* A = Aptr[k0 / F];
        int c0 = k0 % F;
        {
            int lr = tid >> 3, lc = (tid & 7) * 4;
#pragma unroll
            for (int h = 0; h < 2; ++h) {
                int row = r0 + lr + h * 32;
                float4 v = make_float4(0.f, 0.f, 0.f, 0.f);
                if (row < n) v = *reinterpret_cast<const float4*>(A + (size_t)row * F + c0 + lc);
                As[lr + h * 32][lc + 0] = v.x;
                As[lr + h * 32][lc + 1] = v.y;
                As[lr + h * 32][lc + 2] = v.z;
                As[lr + h * 32][lc + 3] = v.w;
            }
            int br = tid >> 4, bc = (tid & 15) * 4;
#pragma unroll
            for (int h = 0; h < 2; ++h) {
                float4 v = *reinterpret_cast<const float4*>(W + (size_t)(k0 + br + h * 16) * 64 + bc);
                *reinterpret_cast<float4*>(&Bs[br + h * 16][bc]) = v;
            }
        }
        __syncthreads();
#pragma unroll
        for (int kk = 0; kk < 32; ++kk) {
            float a[4];
#pragma unroll
            for (int i = 0; i < 4; ++i) a[i] = As[ty * 4 + i][kk];
            float4 bv = *reinterpret_cast<const float4*>(&Bs[kk][tx * 4]);
            float b[4] = {bv.x, bv.y, bv.z, bv.w};
#pragma unroll
            for (int i = 0; i < 4; ++i)
#pragma unroll
                for (int j = 0; j < 4; ++j) c[i][j] += a[i] * b[j];
        }
        __syncthreads();
    }

    float4 b4 = *reinterpret_cast<const float4*>(bias + tx * 4);
    float bb[4] = {b4.x, b4.y, b4.z, b4.w};
#pragma unroll
    for (int i = 0; i < 4; ++i) {
        int row = r0 + ty * 4 + i;
        if (row < n) {
            float4 o;
            float vals[4];
#pragma unroll
            for (int j = 0; j < 4; ++j) {
                float v = c[i][j] + bb[j];
                if (RELU) v = fmaxf(v, 0.f);
                vals[j] = v;
            }
            o.x = vals[0]; o.y = vals[1]; o.z = vals[2]; o.w = vals[3];
            *reinterpret_cast<float4*>(out + (size_t)row * 64 + tx * 4) = o;
        }
    }
}

// ---------------- output layer: 3x(64->5) GEMV + log_softmax ----------------
__global__ __launch_bounds__(256) void out_layer(const float* __restrict__ A0,
                                                 const float* __restrict__ A1,
                                                 const float* __restrict__ A2,
                                                 const float* __restrict__ W,   // [192][5]
                                                 const float* __restrict__ bias,  // [5]
                                                 float* __restrict__ out, int n) {
    __shared__ float Ws[960];
    __shared__ float bs[8];
    int tid = threadIdx.x;
    for (int i = tid; i < 960; i += 256) Ws[i] = W[i];
    if (tid < 5) bs[tid] = bias[tid];
    __syncthreads();
    int nd = blockIdx.x * 256 + tid;
    if (nd >= n) return;
    float acc[5];
#pragma unroll
    for (int c = 0; c < 5; ++c) acc[c] = bs[c];
    const float* Ap[3] = {A0, A1, A2};
#pragma unroll
    for (int m = 0; m < 3; ++m) {
        const float4* a4 = reinterpret_cast<const float4*>(Ap[m] + (size_t)nd * 64);
#pragma unroll
        for (int k4 = 0; k4 < 16; ++k4) {
            float4 av = a4[k4];
            int kb = (m * 64 + k4 * 4) * 5;
#pragma unroll
            for (int c = 0; c < 5; ++c) acc[c] += av.x * Ws[kb + c];
#pragma unroll
            for (int c = 0; c < 5; ++c) acc[c] += av.y * Ws[kb + 5 + c];
#pragma unroll
            for (int c = 0; c < 5; ++c) acc[c] += av.z * Ws[kb + 10 + c];
#pragma unroll
            for (int c = 0; c < 5; ++c) acc[c] += av.w * Ws[kb + 15 + c];
        }
    }
    float mx = acc[0];
#pragma unroll
    for (int c = 1; c < 5; ++c) mx = fmaxf(mx, acc[c]);
    float s = 0.f;
#pragma unroll
    for (int c = 0; c < 5; ++c) s += expf(acc[c] - mx);
    float l = logf(s);
#pragma unroll
    for (int c = 0; c < 5; ++c) out[(size_t)nd * 5 + c] = acc[c] - mx - l;
}

// ---------------- launch ----------------

static inline size_t alignup(size_t v) { return (v + 255) & ~(size_t)255; }

extern "C" void kernel_launch(void* const* d_in, const int* in_sizes, int n_in,
                              void* d_out, int out_size, void* d_ws, size_t ws_size,
                              hipStream_t stream) {
    const float* x  = (const float*)d_in[0];
    const int*   ei = (const int*)d_in[1];
    const float* ew = (const float*)d_in[2];
    const float* W1 = (const float*)d_in[3];
    const float* b1 = (const float*)d_in[4];
    const float* W3 = (const float*)d_in[5];
    const float* b3 = (const float*)d_in[6];
    const float* W4 = (const float*)d_in[7];
    const float* b4 = (const float*)d_in[8];
    float* out = (float*)d_out;

    const int D = 128, H = 64;
    const int N = in_sizes[0] / D;
    const int E = in_sizes[2];
    const int* row = ei;
    const int* col = ei + E;

    char* ws = (char*)d_ws;
    size_t off = 0;
    auto alloc = [&](size_t bytes) { size_t o = off; off += alignup(bytes); return o; };

    float* deg    = (float*)(ws + alloc((size_t)N * 4));
    int*   cnt    = (int*)  (ws + alloc((size_t)(N + 1) * 4));
    int*   rowp   = (int*)  (ws + alloc((size_t)(N + 1) * 4));
    int*   cursor = (int*)  (ws + alloc((size_t)N * 4));
    int*   part   = (int*)  (ws + alloc(256 * 4));
    int*   ci     = (int*)  (ws + alloc((size_t)E * 4));
    float* ev     = (float*)(ws + alloc((size_t)E * 4));
    float* bufA   = (float*)(ws + alloc((size_t)N * D * 4));  // Tx1(L1); later Tx(L2)/Tx(L3)
    float* bufB   = (float*)(ws + alloc((size_t)N * D * 4));  // Tx2(L1)
    float* h1     = (float*)(ws + alloc((size_t)N * H * 4));
    float* h2     = (float*)(ws + alloc((size_t)N * H * 4));

    float* TxD  = bufA;                      // N*64 (layer2 Tx1)
    float* TxE  = bufA + (size_t)N * H;      // N*64 (layer2 Tx2)
    float* Tx1c = bufA;                      // layer3 Tx1 (overwrites dead TxD)
    float* Tx2c = bufA + (size_t)N * H;      // layer3 Tx2

    dim3 blk(256);
    int gE = (E + 255) / 256;
    int gN = (N + 255) / 256;

    hipMemsetAsync(deg, 0, (size_t)N * 4, stream);
    hipMemsetAsync(cnt, 0, (size_t)(N + 1) * 4, stream);

    edge_count_deg<<<gE, blk, 0, stream>>>(row, ew, deg, cnt, E);
    make_dinv<<<gN, blk, 0, stream>>>(deg, N);

    int M = N + 1;
    int nb = (M + 1023) / 1024;
    scan_block<<<nb, blk, 0, stream>>>(cnt, rowp, part, M);
    scan_part_k<<<1, blk, 0, stream>>>(part, nb);
    scan_add<<<(M + 255) / 256, blk, 0, stream>>>(rowp, part, M);
    copy_int<<<gN, blk, 0, stream>>>(rowp, cursor, N);
    edge_fill<<<gE, blk, 0, stream>>>(row, col, ew, deg, cursor, ci, ev, E);

    // ---- layer 1 (F=128 -> 64, relu) ----
    int g128 = (N + 7) / 8;    // 8 rows/block for F=128
    int g64  = (N + 15) / 16;  // 16 rows/block for F=64
    int gG   = (N + 63) / 64;
    spmm_csr<128, false><<<g128, blk, 0, stream>>>(rowp, ci, ev, x, nullptr, bufA, N);
    spmm_csr<128, true ><<<g128, blk, 0, stream>>>(rowp, ci, ev, bufA, x, bufB, N);
    gemm3<128, true><<<gG, blk, 0, stream>>>(x, bufA, bufB, W1, b1, h1, N);

    // ---- layer 2 (F=64 -> 64, relu) ----
    spmm_csr<64, false><<<g64, blk, 0, stream>>>(rowp, ci, ev, h1, nullptr, TxD, N);
    spmm_csr<64, true ><<<g64, blk, 0, stream>>>(rowp, ci, ev, TxD, h1, TxE, N);
    gemm3<64, true><<<gG, blk, 0, stream>>>(h1, TxD, TxE, W3, b3, h2, N);

    // ---- layer 3 (F=64 -> 5) + log_softmax ----
    spmm_csr<64, false><<<g64, blk, 0, stream>>>(rowp, ci, ev, h2, nullptr, Tx1c, N);
    spmm_csr<64, true ><<<g64, blk, 0, stream>>>(rowp, ci, ev, Tx1c, h2, Tx2c, N);
    out_layer<<<gN, blk, 0, stream>>>(h2, Tx1c, Tx2c, W4, b4, out, N);
}

// Round 2
// 815.259 us; speedup vs baseline: 1.1494x; 1.1494x over previous
//
#include <hip/hip_runtime.h>
#include <cstdint>
#include <cstddef>

// ---------------- CSR build (1 atomic per edge total) ----------------

// pass 1: count edges per row; the atomic's return value IS the within-row slot
__global__ void pass1_count(const int* __restrict__ row, int* __restrict__ cnt,
                            int* __restrict__ off, int E) {
    int e = blockIdx.x * blockDim.x + threadIdx.x;
    if (e < E) off[e] = atomicAdd(&cnt[row[e]], 1);
}

// exclusive scan over n ints: per-block (1024 elems) scan + partials
__global__ void scan_block(const int* __restrict__ in, int* __restrict__ out,
                           int* __restrict__ part, int n) {
    __shared__ int sh[256];
    int tid = threadIdx.x;
    int base = blockIdx.x * 1024 + tid * 4;
    int v[4];
#pragma unroll
    for (int j = 0; j < 4; ++j) v[j] = (base + j < n) ? in[base + j] : 0;
    int s = v[0] + v[1] + v[2] + v[3];
    sh[tid] = s;
    __syncthreads();
    for (int off = 1; off < 256; off <<= 1) {
        int t = (tid >= off) ? sh[tid - off] : 0;
        __syncthreads();
        sh[tid] += t;
        __syncthreads();
    }
    int run = sh[tid] - s;  // exclusive prefix for this thread
#pragma unroll
    for (int j = 0; j < 4; ++j) {
        if (base + j < n) out[base + j] = run;
        run += v[j];
    }
    if (tid == 255) part[blockIdx.x] = sh[255];
}

__global__ void scan_part_k(int* __restrict__ part, int nb) {
    __shared__ int sh[256];
    int tid = threadIdx.x;
    int v = (tid < nb) ? part[tid] : 0;
    sh[tid] = v;
    __syncthreads();
    for (int off = 1; off < 256; off <<= 1) {
        int t = (tid >= off) ? sh[tid - off] : 0;
        __syncthreads();
        sh[tid] += t;
        __syncthreads();
    }
    if (tid < nb) part[tid] = sh[tid] - v;
}

__global__ void scan_add(int* __restrict__ out, const int* __restrict__ part, int n) {
    int i = blockIdx.x * blockDim.x + threadIdx.x;
    if (i < n) out[i] += part[i >> 10];
}

// pass 2: place (col, raw weight) at rowp[r]+off[e]; no atomics
__global__ void pass2_fill(const int* __restrict__ row, const int* __restrict__ col,
                           const float* __restrict__ w, const int* __restrict__ rowp,
                           const int* __restrict__ off, int2* __restrict__ meta, int E) {
    int e = blockIdx.x * blockDim.x + threadIdx.x;
    if (e < E) {
        int r = row[e];
        int idx = rowp[r] + off[e];
        int2 v;
        v.x = col[e];
        v.y = __float_as_int(w[e]);
        meta[idx] = v;
    }
}

// per-row: deg = sum of raw weights over the row's CSR segment -> dinv = rsqrt
__global__ void row_dinv(const int* __restrict__ rowp, const int2* __restrict__ meta,
                         float* __restrict__ dinv, int n) {
    int r = blockIdx.x * blockDim.x + threadIdx.x;
    if (r >= n) return;
    int e0 = rowp[r], e1 = rowp[r + 1];
    float s = 0.f;
    for (int e = e0; e < e1; ++e) s += __int_as_float(meta[e].y);
    dinv[r] = s > 0.f ? rsqrtf(s) : 0.f;
}

// per-row: ev[e] = -dinv[r] * w * dinv[col[e]] in place
__global__ void scale_ev(const int* __restrict__ rowp, int2* __restrict__ meta,
                         const float* __restrict__ dinv, int n) {
    int r = blockIdx.x * blockDim.x + threadIdx.x;
    if (r >= n) return;
    int e0 = rowp[r], e1 = rowp[r + 1];
    float dr = dinv[r];
    for (int e = e0; e < e1; ++e) {
        int2 v = meta[e];
        float w = __int_as_float(v.y);
        v.y = __float_as_int(-dr * w * dinv[v.x]);
        meta[e] = v;
    }
}

// ---------------- SpMM (CSR) ----------------
// y[r][:] = sum_e norm[e] * x[col[e]][:]               (AXPBY=false)
// y[r][:] = 2*sum_e norm[e] * x[col[e]][:] - z[r][:]   (AXPBY=true)
template <int F, bool AXPBY>
__global__ __launch_bounds__(256) void spmm_csr(const int* __restrict__ rp,
                                                const int2* __restrict__ meta,
                                                const float* __restrict__ x,
                                                const float* __restrict__ z,
                                                float* __restrict__ y, int n) {
    constexpr int TPR = F / 4;                 // threads per row (float4 each)
    constexpr int RPB = 256 / TPR;             // rows per block
    int r = blockIdx.x * RPB + threadIdx.x / TPR;
    if (r >= n) return;
    int f = (threadIdx.x % TPR) * 4;
    int e0 = rp[r], e1 = rp[r + 1];
    float4 acc = make_float4(0.f, 0.f, 0.f, 0.f);
    for (int e = e0; e < e1; ++e) {
        int2 m = meta[e];
        float w = __int_as_float(m.y);
        const float4 xv = *reinterpret_cast<const float4*>(x + (size_t)m.x * F + f);
        acc.x += w * xv.x;
        acc.y += w * xv.y;
        acc.z += w * xv.z;
        acc.w += w * xv.w;
    }
    if (AXPBY) {
        const float4 zv = *reinterpret_cast<const float4*>(z + (size_t)r * F + f);
        acc.x = 2.f * acc.x - zv.x;
        acc.y = 2.f * acc.y - zv.y;
        acc.z = 2.f * acc.z - zv.z;
        acc.w = 2.f * acc.w - zv.w;
    }
    *reinterpret_cast<float4*>(y + (size_t)r * F + f) = acc;
}

// ---------------- 3-operand GEMM ----------------
// out[n][64] = act( A0@W[0:F] + A1@W[F:2F] + A2@W[2F:3F] + bias )
// W is contiguous [3F][64] row-major (exactly the (3,F,64) input layout).
template <int F, bool RELU>
__global__ __launch_bounds__(256) void gemm3(const float* __restrict__ A0,
                                             const float* __restrict__ A1,
                                             const float* __restrict__ A2,
                                             const float* __restrict__ W,
                                             const float* __restrict__ bias,
                                             float* __restrict__ out, int n) {
    __shared__ float As[64][33];
    __shared__ float Bs[32][64];
    const float* Aptr[3] = {A0, A1, A2};
    int tid = threadIdx.x;
    int r0 = blockIdx.x * 64;
    int tx = tid & 15, ty = tid >> 4;  // 16x16 threads, 4x4 micro-tile
    float c[4][4] = {};

    constexpr int KT = 3 * F / 32;
    for (int kt = 0; kt < KT; ++kt) {
        int k0 = kt * 32;
        const float* A = Aptr[k0 / F];
        int c0 = k0 % F;
        {
            int lr = tid >> 3, lc = (tid & 7) * 4;
#pragma unroll
            for (int h = 0; h < 2; ++h) {
                int row = r0 + lr + h * 32;
                float4 v = make_float4(0.f, 0.f, 0.f, 0.f);
                if (row < n) v = *reinterpret_cast<const float4*>(A + (size_t)row * F + c0 + lc);
                As[lr + h * 32][lc + 0] = v.x;
                As[lr + h * 32][lc + 1] = v.y;
                As[lr + h * 32][lc + 2] = v.z;
                As[lr + h * 32][lc + 3] = v.w;
            }
            int br = tid >> 4, bc = (tid & 15) * 4;
#pragma unroll
            for (int h = 0; h < 2; ++h) {
                float4 v = *reinterpret_cast<const float4*>(W + (size_t)(k0 + br + h * 16) * 64 + bc);
                *reinterpret_cast<float4*>(&Bs[br + h * 16][bc]) = v;
            }
        }
        __syncthreads();
#pragma unroll
        for (int kk = 0; kk < 32; ++kk) {
            float a[4];
#pragma unroll
            for (int i = 0; i < 4; ++i) a[i] = As[ty * 4 + i][kk];
            float4 bv = *reinterpret_cast<const float4*>(&Bs[kk][tx * 4]);
            float b[4] = {bv.x, bv.y, bv.z, bv.w};
#pragma unroll
            for (int i = 0; i < 4; ++i)
#pragma unroll
                for (int j = 0; j < 4; ++j) c[i][j] += a[i] * b[j];
        }
        __syncthreads();
    }

    float4 b4 = *reinterpret_cast<const float4*>(bias + tx * 4);
    float bb[4] = {b4.x, b4.y, b4.z, b4.w};
#pragma unroll
    for (int i = 0; i < 4; ++i) {
        int row = r0 + ty * 4 + i;
        if (row < n) {
            float4 o;
            float vals[4];
#pragma unroll
            for (int j = 0; j < 4; ++j) {
                float v = c[i][j] + bb[j];
                if (RELU) v = fmaxf(v, 0.f);
                vals[j] = v;
            }
            o.x = vals[0]; o.y = vals[1]; o.z = vals[2]; o.w = vals[3];
            *reinterpret_cast<float4*>(out + (size_t)row * 64 + tx * 4) = o;
        }
    }
}

// ---------------- output layer: 3x(64->5) GEMV + log_softmax ----------------
__global__ __launch_bounds__(256) void out_layer(const float* __restrict__ A0,
                                                 const float* __restrict__ A1,
                                                 const float* __restrict__ A2,
                                                 const float* __restrict__ W,   // [192][5]
                                                 const float* __restrict__ bias,  // [5]
                                                 float* __restrict__ out, int n) {
    __shared__ float Ws[960];
    __shared__ float bs[8];
    int tid = threadIdx.x;
    for (int i = tid; i < 960; i += 256) Ws[i] = W[i];
    if (tid < 5) bs[tid] = bias[tid];
    __syncthreads();
    int nd = blockIdx.x * 256 + tid;
    if (nd >= n) return;
    float acc[5];
#pragma unroll
    for (int c = 0; c < 5; ++c) acc[c] = bs[c];
    const float* Ap[3] = {A0, A1, A2};
#pragma unroll
    for (int m = 0; m < 3; ++m) {
        const float4* a4 = reinterpret_cast<const float4*>(Ap[m] + (size_t)nd * 64);
#pragma unroll
        for (int k4 = 0; k4 < 16; ++k4) {
            float4 av = a4[k4];
            int kb = (m * 64 + k4 * 4) * 5;
#pragma unroll
            for (int c = 0; c < 5; ++c) acc[c] += av.x * Ws[kb + c];
#pragma unroll
            for (int c = 0; c < 5; ++c) acc[c] += av.y * Ws[kb + 5 + c];
#pragma unroll
            for (int c = 0; c < 5; ++c) acc[c] += av.z * Ws[kb + 10 + c];
#pragma unroll
            for (int c = 0; c < 5; ++c) acc[c] += av.w * Ws[kb + 15 + c];
        }
    }
    float mx = acc[0];
#pragma unroll
    for (int c = 1; c < 5; ++c) mx = fmaxf(mx, acc[c]);
    float s = 0.f;
#pragma unroll
    for (int c = 0; c < 5; ++c) s += expf(acc[c] - mx);
    float l = logf(s);
#pragma unroll
    for (int c = 0; c < 5; ++c) out[(size_t)nd * 5 + c] = acc[c] - mx - l;
}

// ---------------- launch ----------------

static inline size_t alignup(size_t v) { return (v + 255) & ~(size_t)255; }

extern "C" void kernel_launch(void* const* d_in, const int* in_sizes, int n_in,
                              void* d_out, int out_size, void* d_ws, size_t ws_size,
                              hipStream_t stream) {
    const float* x  = (const float*)d_in[0];
    const int*   ei = (const int*)d_in[1];
    const float* ew = (const float*)d_in[2];
    const float* W1 = (const float*)d_in[3];
    const float* b1 = (const float*)d_in[4];
    const float* W3 = (const float*)d_in[5];
    const float* b3 = (const float*)d_in[6];
    const float* W4 = (const float*)d_in[7];
    const float* b4 = (const float*)d_in[8];
    float* out = (float*)d_out;

    const int D = 128, H = 64;
    const int N = in_sizes[0] / D;
    const int E = in_sizes[2];
    const int* row = ei;
    const int* col = ei + E;

    char* ws = (char*)d_ws;
    size_t off = 0;
    auto alloc = [&](size_t bytes) { size_t o = off; off += alignup(bytes); return o; };

    float* dinv = (float*)(ws + alloc((size_t)N * 4));
    int*   cnt  = (int*)  (ws + alloc((size_t)(N + 1) * 4));
    int*   rowp = (int*)  (ws + alloc((size_t)(N + 1) * 4));
    int*   part = (int*)  (ws + alloc(256 * 4));
    int2*  meta = (int2*) (ws + alloc((size_t)E * 8));
    float* bufA = (float*)(ws + alloc((size_t)N * D * 4));  // Tx1(L1); later Tx(L2)/Tx(L3)
    float* bufB = (float*)(ws + alloc((size_t)N * D * 4));  // Tx2(L1)
    float* h1   = (float*)(ws + alloc((size_t)N * H * 4));
    float* h2   = (float*)(ws + alloc((size_t)N * H * 4));

    // off[] is only live during CSR build, before bufA's first use -> alias it
    int* offBuf = (int*)bufA;

    float* TxD  = bufA;                      // N*64 (layer2 Tx1)
    float* TxE  = bufA + (size_t)N * H;      // N*64 (layer2 Tx2)
    float* Tx1c = bufA;                      // layer3 Tx1 (overwrites dead TxD)
    float* Tx2c = bufA + (size_t)N * H;      // layer3 Tx2

    dim3 blk(256);
    int gE = (E + 255) / 256;
    int gN = (N + 255) / 256;

    hipMemsetAsync(cnt, 0, (size_t)(N + 1) * 4, stream);

    pass1_count<<<gE, blk, 0, stream>>>(row, cnt, offBuf, E);

    int M = N + 1;
    int nb = (M + 1023) / 1024;
    scan_block<<<nb, blk, 0, stream>>>(cnt, rowp, part, M);
    scan_part_k<<<1, blk, 0, stream>>>(part, nb);
    scan_add<<<(M + 255) / 256, blk, 0, stream>>>(rowp, part, M);

    pass2_fill<<<gE, blk, 0, stream>>>(row, col, ew, rowp, offBuf, meta, E);
    row_dinv<<<gN, blk, 0, stream>>>(rowp, meta, dinv, N);
    scale_ev<<<gN, blk, 0, stream>>>(rowp, meta, dinv, N);

    // ---- layer 1 (F=128 -> 64, relu) ----
    int g128 = (N + 7) / 8;    // 8 rows/block for F=128
    int g64  = (N + 15) / 16;  // 16 rows/block for F=64
    int gG   = (N + 63) / 64;
    spmm_csr<128, false><<<g128, blk, 0, stream>>>(rowp, meta, x, nullptr, bufA, N);
    spmm_csr<128, true ><<<g128, blk, 0, stream>>>(rowp, meta, bufA, x, bufB, N);
    gemm3<128, true><<<gG, blk, 0, stream>>>(x, bufA, bufB, W1, b1, h1, N);

    // ---- layer 2 (F=64 -> 64, relu) ----
    spmm_csr<64, false><<<g64, blk, 0, stream>>>(rowp, meta, h1, nullptr, TxD, N);
    spmm_csr<64, true ><<<g64, blk, 0, stream>>>(rowp, meta, TxD, h1, TxE, N);
    gemm3<64, true><<<gG, blk, 0, stream>>>(h1, TxD, TxE, W3, b3, h2, N);

    // ---- layer 3 (F=64 -> 5) + log_softmax ----
    spmm_csr<64, false><<<g64, blk, 0, stream>>>(rowp, meta, h2, nullptr, Tx1c, N);
    spmm_csr<64, true ><<<g64, blk, 0, stream>>>(rowp, meta, Tx1c, h2, Tx2c, N);
    out_layer<<<gN, blk, 0, stream>>>(h2, Tx1c, Tx2c, W4, b4, out, N);
}

// Round 3
// 599.961 us; speedup vs baseline: 1.5619x; 1.3589x over previous
//
#include <hip/hip_runtime.h>
#include <cstdint>
#include <cstddef>

typedef unsigned short u16;

// ---------------- bf16 helpers (RNE) ----------------
__device__ __forceinline__ float bflo(unsigned u) { return __uint_as_float(u << 16); }
__device__ __forceinline__ float bfhi(unsigned u) { return __uint_as_float(u & 0xFFFF0000u); }
__device__ __forceinline__ u16 f2bf(float f) {
    unsigned u = __float_as_uint(f);
    u += 0x7FFFu + ((u >> 16) & 1u);
    return (u16)(u >> 16);
}
__device__ __forceinline__ unsigned pack2(float a, float b) {
    return (unsigned)f2bf(a) | ((unsigned)f2bf(b) << 16);
}

// ---------------- CSR build (1 atomic per edge total) ----------------

__global__ void pass1_count(const int* __restrict__ row, int* __restrict__ cnt,
                            int* __restrict__ off, int E) {
    int e = blockIdx.x * blockDim.x + threadIdx.x;
    if (e < E) off[e] = atomicAdd(&cnt[row[e]], 1);
}

__global__ void scan_block(const int* __restrict__ in, int* __restrict__ out,
                           int* __restrict__ part, int n) {
    __shared__ int sh[256];
    int tid = threadIdx.x;
    int base = blockIdx.x * 1024 + tid * 4;
    int v[4];
#pragma unroll
    for (int j = 0; j < 4; ++j) v[j] = (base + j < n) ? in[base + j] : 0;
    int s = v[0] + v[1] + v[2] + v[3];
    sh[tid] = s;
    __syncthreads();
    for (int off = 1; off < 256; off <<= 1) {
        int t = (tid >= off) ? sh[tid - off] : 0;
        __syncthreads();
        sh[tid] += t;
        __syncthreads();
    }
    int run = sh[tid] - s;
#pragma unroll
    for (int j = 0; j < 4; ++j) {
        if (base + j < n) out[base + j] = run;
        run += v[j];
    }
    if (tid == 255) part[blockIdx.x] = sh[255];
}

__global__ void scan_part_k(int* __restrict__ part, int nb) {
    __shared__ int sh[256];
    int tid = threadIdx.x;
    int v = (tid < nb) ? part[tid] : 0;
    sh[tid] = v;
    __syncthreads();
    for (int off = 1; off < 256; off <<= 1) {
        int t = (tid >= off) ? sh[tid - off] : 0;
        __syncthreads();
        sh[tid] += t;
        __syncthreads();
    }
    if (tid < nb) part[tid] = sh[tid] - v;
}

__global__ void scan_add(int* __restrict__ out, const int* __restrict__ part, int n) {
    int i = blockIdx.x * blockDim.x + threadIdx.x;
    if (i < n) out[i] += part[i >> 10];
}

__global__ void pass2_fill(const int* __restrict__ row, const int* __restrict__ col,
                           const float* __restrict__ w, const int* __restrict__ rowp,
                           const int* __restrict__ off, int2* __restrict__ meta, int E) {
    int e = blockIdx.x * blockDim.x + threadIdx.x;
    if (e < E) {
        int r = row[e];
        int idx = rowp[r] + off[e];
        int2 v;
        v.x = col[e];
        v.y = __float_as_int(w[e]);
        meta[idx] = v;
    }
}

__global__ void row_dinv(const int* __restrict__ rowp, const int2* __restrict__ meta,
                         float* __restrict__ dinv, int n) {
    int r = blockIdx.x * blockDim.x + threadIdx.x;
    if (r >= n) return;
    int e0 = rowp[r], e1 = rowp[r + 1];
    float s = 0.f;
    for (int e = e0; e < e1; ++e) s += __int_as_float(meta[e].y);
    dinv[r] = s > 0.f ? rsqrtf(s) : 0.f;
}

__global__ void scale_ev(const int* __restrict__ rowp, int2* __restrict__ meta,
                         const float* __restrict__ dinv, int n) {
    int r = blockIdx.x * blockDim.x + threadIdx.x;
    if (r >= n) return;
    int e0 = rowp[r], e1 = rowp[r + 1];
    float dr = dinv[r];
    for (int e = e0; e < e1; ++e) {
        int2 v = meta[e];
        float w = __int_as_float(v.y);
        v.y = __float_as_int(-dr * w * dinv[v.x]);
        meta[e] = v;
    }
}

// ---------------- fp32 -> bf16 bulk convert ----------------
__global__ void to_bf16(const float* __restrict__ in, unsigned* __restrict__ out, int n2) {
    int i = blockIdx.x * blockDim.x + threadIdx.x;  // 2 floats per thread
    if (i < n2) {
        float2 v = reinterpret_cast<const float2*>(in)[i];
        out[i] = pack2(v.x, v.y);
    }
}

// ---------------- SpMM (CSR), bf16 operand, fp32 accumulate ----------------
// y = L*x            (AXPBY=false)
// y = 2*L*x - z      (AXPBY=true)
template <int F, bool AXPBY>
__global__ __launch_bounds__(256) void spmm_bf16(const int* __restrict__ rp,
                                                 const int2* __restrict__ meta,
                                                 const u16* __restrict__ x,
                                                 const u16* __restrict__ z,
                                                 u16* __restrict__ y, int n) {
    constexpr int TPR = F / 8;                 // threads per row (8 bf16 = uint4 each)
    constexpr int RPB = 256 / TPR;
    int r = blockIdx.x * RPB + threadIdx.x / TPR;
    if (r >= n) return;
    int f = (threadIdx.x % TPR) * 8;
    int e0 = rp[r], e1 = rp[r + 1];
    float acc[8] = {0.f, 0.f, 0.f, 0.f, 0.f, 0.f, 0.f, 0.f};
    for (int e = e0; e < e1; ++e) {
        int2 m = meta[e];
        float w = __int_as_float(m.y);
        uint4 xv = *reinterpret_cast<const uint4*>(x + (size_t)m.x * F + f);
        acc[0] += w * bflo(xv.x); acc[1] += w * bfhi(xv.x);
        acc[2] += w * bflo(xv.y); acc[3] += w * bfhi(xv.y);
        acc[4] += w * bflo(xv.z); acc[5] += w * bfhi(xv.z);
        acc[6] += w * bflo(xv.w); acc[7] += w * bfhi(xv.w);
    }
    if (AXPBY) {
        uint4 zv = *reinterpret_cast<const uint4*>(z + (size_t)r * F + f);
        acc[0] = 2.f * acc[0] - bflo(zv.x); acc[1] = 2.f * acc[1] - bfhi(zv.x);
        acc[2] = 2.f * acc[2] - bflo(zv.y); acc[3] = 2.f * acc[3] - bfhi(zv.y);
        acc[4] = 2.f * acc[4] - bflo(zv.z); acc[5] = 2.f * acc[5] - bfhi(zv.z);
        acc[6] = 2.f * acc[6] - bflo(zv.w); acc[7] = 2.f * acc[7] - bfhi(zv.w);
    }
    uint4 o;
    o.x = pack2(acc[0], acc[1]);
    o.y = pack2(acc[2], acc[3]);
    o.z = pack2(acc[4], acc[5]);
    o.w = pack2(acc[6], acc[7]);
    *reinterpret_cast<uint4*>(y + (size_t)r * F + f) = o;
}

// ---------------- 3-operand GEMM (bf16 A, fp32 W/acc, bf16 out) ----------------
// out[n][64] = act( A0@W[0:F] + A1@W[F:2F] + A2@W[2F:3F] + bias )
template <int F, bool RELU>
__global__ __launch_bounds__(256) void gemm3(const u16* __restrict__ A0,
                                             const u16* __restrict__ A1,
                                             const u16* __restrict__ A2,
                                             const float* __restrict__ W,
                                             const float* __restrict__ bias,
                                             u16* __restrict__ out, int n) {
    __shared__ float As[64][33];
    __shared__ float Bs[32][64];
    const u16* Aptr[3] = {A0, A1, A2};
    int tid = threadIdx.x;
    int r0 = blockIdx.x * 64;
    int tx = tid & 15, ty = tid >> 4;  // 16x16 threads, 4x4 micro-tile
    float c[4][4] = {};

    constexpr int KT = 3 * F / 32;
    for (int kt = 0; kt < KT; ++kt) {
        int k0 = kt * 32;
        const u16* A = Aptr[k0 / F];
        int c0 = k0 % F;
        {
            // A tile: 64 rows x 32 cols bf16; one uint4 (8 bf16) per thread
            int lr = tid >> 2, lc = (tid & 3) * 8;
            int row = r0 + lr;
            uint4 v = make_uint4(0u, 0u, 0u, 0u);
            if (row < n) v = *reinterpret_cast<const uint4*>(A + (size_t)row * F + c0 + lc);
            As[lr][lc + 0] = bflo(v.x); As[lr][lc + 1] = bfhi(v.x);
            As[lr][lc + 2] = bflo(v.y); As[lr][lc + 3] = bfhi(v.y);
            As[lr][lc + 4] = bflo(v.z); As[lr][lc + 5] = bfhi(v.z);
            As[lr][lc + 6] = bflo(v.w); As[lr][lc + 7] = bfhi(v.w);
            // W tile: 32 rows x 64 cols fp32
            int br = tid >> 4, bc = (tid & 15) * 4;
#pragma unroll
            for (int h = 0; h < 2; ++h) {
                float4 v2 = *reinterpret_cast<const float4*>(W + (size_t)(k0 + br + h * 16) * 64 + bc);
                *reinterpret_cast<float4*>(&Bs[br + h * 16][bc]) = v2;
            }
        }
        __syncthreads();
#pragma unroll
        for (int kk = 0; kk < 32; ++kk) {
            float a[4];
#pragma unroll
            for (int i = 0; i < 4; ++i) a[i] = As[ty * 4 + i][kk];
            float4 bv = *reinterpret_cast<const float4*>(&Bs[kk][tx * 4]);
            float b[4] = {bv.x, bv.y, bv.z, bv.w};
#pragma unroll
            for (int i = 0; i < 4; ++i)
#pragma unroll
                for (int j = 0; j < 4; ++j) c[i][j] += a[i] * b[j];
        }
        __syncthreads();
    }

    float4 b4 = *reinterpret_cast<const float4*>(bias + tx * 4);
    float bb[4] = {b4.x, b4.y, b4.z, b4.w};
#pragma unroll
    for (int i = 0; i < 4; ++i) {
        int row = r0 + ty * 4 + i;
        if (row < n) {
            float v0 = c[i][0] + bb[0], v1 = c[i][1] + bb[1];
            float v2 = c[i][2] + bb[2], v3 = c[i][3] + bb[3];
            if (RELU) {
                v0 = fmaxf(v0, 0.f); v1 = fmaxf(v1, 0.f);
                v2 = fmaxf(v2, 0.f); v3 = fmaxf(v3, 0.f);
            }
            uint2 o;
            o.x = pack2(v0, v1);
            o.y = pack2(v2, v3);
            *reinterpret_cast<uint2*>(out + (size_t)row * 64 + tx * 4) = o;
        }
    }
}

// ---------------- output layer: 3x(64->5) GEMV + log_softmax ----------------
__global__ __launch_bounds__(256) void out_layer(const u16* __restrict__ A0,
                                                 const u16* __restrict__ A1,
                                                 const u16* __restrict__ A2,
                                                 const float* __restrict__ W,    // [192][5]
                                                 const float* __restrict__ bias, // [5]
                                                 float* __restrict__ out, int n) {
    __shared__ float Ws[960];
    __shared__ float bs[8];
    int tid = threadIdx.x;
    for (int i = tid; i < 960; i += 256) Ws[i] = W[i];
    if (tid < 5) bs[tid] = bias[tid];
    __syncthreads();
    int nd = blockIdx.x * 256 + tid;
    if (nd >= n) return;
    float acc[5];
#pragma unroll
    for (int c = 0; c < 5; ++c) acc[c] = bs[c];
    const u16* Ap[3] = {A0, A1, A2};
#pragma unroll
    for (int m = 0; m < 3; ++m) {
        const uint4* a4 = reinterpret_cast<const uint4*>(Ap[m] + (size_t)nd * 64);
#pragma unroll
        for (int k8 = 0; k8 < 8; ++k8) {
            uint4 av = a4[k8];
            float a[8] = {bflo(av.x), bfhi(av.x), bflo(av.y), bfhi(av.y),
                          bflo(av.z), bfhi(av.z), bflo(av.w), bfhi(av.w)};
            int kb = (m * 64 + k8 * 8) * 5;
#pragma unroll
            for (int j = 0; j < 8; ++j)
#pragma unroll
                for (int c = 0; c < 5; ++c) acc[c] += a[j] * Ws[kb + 5 * j + c];
        }
    }
    float mx = acc[0];
#pragma unroll
    for (int c = 1; c < 5; ++c) mx = fmaxf(mx, acc[c]);
    float s = 0.f;
#pragma unroll
    for (int c = 0; c < 5; ++c) s += expf(acc[c] - mx);
    float l = logf(s);
#pragma unroll
    for (int c = 0; c < 5; ++c) out[(size_t)nd * 5 + c] = acc[c] - mx - l;
}

// ---------------- launch ----------------

static inline size_t alignup(size_t v) { return (v + 255) & ~(size_t)255; }

extern "C" void kernel_launch(void* const* d_in, const int* in_sizes, int n_in,
                              void* d_out, int out_size, void* d_ws, size_t ws_size,
                              hipStream_t stream) {
    const float* x  = (const float*)d_in[0];
    const int*   ei = (const int*)d_in[1];
    const float* ew = (const float*)d_in[2];
    const float* W1 = (const float*)d_in[3];
    const float* b1 = (const float*)d_in[4];
    const float* W3 = (const float*)d_in[5];
    const float* b3 = (const float*)d_in[6];
    const float* W4 = (const float*)d_in[7];
    const float* b4 = (const float*)d_in[8];
    float* out = (float*)d_out;

    const int D = 128, H = 64;
    const int N = in_sizes[0] / D;
    const int E = in_sizes[2];
    const int* row = ei;
    const int* col = ei + E;

    char* ws = (char*)d_ws;
    size_t off = 0;
    auto alloc = [&](size_t bytes) { size_t o = off; off += alignup(bytes); return o; };

    float* dinv = (float*)(ws + alloc((size_t)N * 4));
    int*   cnt  = (int*)  (ws + alloc((size_t)(N + 1) * 4));
    int*   rowp = (int*)  (ws + alloc((size_t)(N + 1) * 4));
    int*   part = (int*)  (ws + alloc(256 * 4));
    int2*  meta = (int2*) (ws + alloc((size_t)E * 8));
    u16*   xb   = (u16*)  (ws + alloc((size_t)N * D * 2));   // x in bf16
    u16*   bufA = (u16*)  (ws + alloc((size_t)N * D * 2));   // Tx1(L1); later Tx(L2)/Tx(L3)
    u16*   bufB = (u16*)  (ws + alloc((size_t)N * D * 2));   // Tx2(L1)
    u16*   h1   = (u16*)  (ws + alloc((size_t)N * H * 2));
    u16*   h2   = (u16*)  (ws + alloc((size_t)N * H * 2));

    // off[] is only live during CSR build, before bufA's first use -> alias it
    int* offBuf = (int*)bufA;

    u16* TxD  = bufA;                      // N*64 (layer2 Tx1)
    u16* TxE  = bufA + (size_t)N * H;      // N*64 (layer2 Tx2)
    u16* Tx1c = bufA;                      // layer3 Tx1
    u16* Tx2c = bufA + (size_t)N * H;      // layer3 Tx2

    dim3 blk(256);
    int gE = (E + 255) / 256;
    int gN = (N + 255) / 256;

    hipMemsetAsync(cnt, 0, (size_t)(N + 1) * 4, stream);

    pass1_count<<<gE, blk, 0, stream>>>(row, cnt, offBuf, E);

    int M = N + 1;
    int nb = (M + 1023) / 1024;
    scan_block<<<nb, blk, 0, stream>>>(cnt, rowp, part, M);
    scan_part_k<<<1, blk, 0, stream>>>(part, nb);
    scan_add<<<(M + 255) / 256, blk, 0, stream>>>(rowp, part, M);

    pass2_fill<<<gE, blk, 0, stream>>>(row, col, ew, rowp, offBuf, meta, E);
    row_dinv<<<gN, blk, 0, stream>>>(rowp, meta, dinv, N);
    scale_ev<<<gN, blk, 0, stream>>>(rowp, meta, dinv, N);

    int n2 = N * D / 2;
    to_bf16<<<(n2 + 255) / 256, blk, 0, stream>>>(x, (unsigned*)xb, n2);

    // ---- layer 1 (F=128 -> 64, relu) ----
    int g128 = (N + 15) / 16;  // 16 rows/block for F=128
    int g64  = (N + 31) / 32;  // 32 rows/block for F=64
    int gG   = (N + 63) / 64;
    spmm_bf16<128, false><<<g128, blk, 0, stream>>>(rowp, meta, xb, nullptr, bufA, N);
    spmm_bf16<128, true ><<<g128, blk, 0, stream>>>(rowp, meta, bufA, xb, bufB, N);
    gemm3<128, true><<<gG, blk, 0, stream>>>(xb, bufA, bufB, W1, b1, h1, N);

    // ---- layer 2 (F=64 -> 64, relu) ----
    spmm_bf16<64, false><<<g64, blk, 0, stream>>>(rowp, meta, h1, nullptr, TxD, N);
    spmm_bf16<64, true ><<<g64, blk, 0, stream>>>(rowp, meta, TxD, h1, TxE, N);
    gemm3<64, true><<<gG, blk, 0, stream>>>(h1, TxD, TxE, W3, b3, h2, N);

    // ---- layer 3 (F=64 -> 5) + log_softmax ----
    spmm_bf16<64, false><<<g64, blk, 0, stream>>>(rowp, meta, h2, nullptr, Tx1c, N);
    spmm_bf16<64, true ><<<g64, blk, 0, stream>>>(rowp, meta, Tx1c, h2, Tx2c, N);
    out_layer<<<gN, blk, 0, stream>>>(h2, Tx1c, Tx2c, W4, b4, out, N);
}

// Round 4
// 526.650 us; speedup vs baseline: 1.7793x; 1.1392x over previous
//
#include <hip/hip_runtime.h>
#include <cstdint>
#include <cstddef>

typedef unsigned short u16;
typedef __attribute__((ext_vector_type(8))) short bf16x8;
typedef __attribute__((ext_vector_type(4))) float f32x4;

// ---------------- bf16 helpers (RNE) ----------------
__device__ __forceinline__ float bflo(unsigned u) { return __uint_as_float(u << 16); }
__device__ __forceinline__ float bfhi(unsigned u) { return __uint_as_float(u & 0xFFFF0000u); }
__device__ __forceinline__ u16 f2bf(float f) {
    unsigned u = __float_as_uint(f);
    u += 0x7FFFu + ((u >> 16) & 1u);
    return (u16)(u >> 16);
}
__device__ __forceinline__ unsigned pack2(float a, float b) {
    return (unsigned)f2bf(a) | ((unsigned)f2bf(b) << 16);
}

// ---------------- CSR build (1 atomic per edge total) ----------------

__global__ void pass1_count(const int* __restrict__ row, int* __restrict__ cnt,
                            int* __restrict__ off, int E) {
    int e = blockIdx.x * blockDim.x + threadIdx.x;
    if (e < E) off[e] = atomicAdd(&cnt[row[e]], 1);
}

__global__ void scan_block(const int* __restrict__ in, int* __restrict__ out,
                           int* __restrict__ part, int n) {
    __shared__ int sh[256];
    int tid = threadIdx.x;
    int base = blockIdx.x * 1024 + tid * 4;
    int v[4];
#pragma unroll
    for (int j = 0; j < 4; ++j) v[j] = (base + j < n) ? in[base + j] : 0;
    int s = v[0] + v[1] + v[2] + v[3];
    sh[tid] = s;
    __syncthreads();
    for (int off = 1; off < 256; off <<= 1) {
        int t = (tid >= off) ? sh[tid - off] : 0;
        __syncthreads();
        sh[tid] += t;
        __syncthreads();
    }
    int run = sh[tid] - s;
#pragma unroll
    for (int j = 0; j < 4; ++j) {
        if (base + j < n) out[base + j] = run;
        run += v[j];
    }
    if (tid == 255) part[blockIdx.x] = sh[255];
}

__global__ void scan_part_k(int* __restrict__ part, int nb) {
    __shared__ int sh[256];
    int tid = threadIdx.x;
    int v = (tid < nb) ? part[tid] : 0;
    sh[tid] = v;
    __syncthreads();
    for (int off = 1; off < 256; off <<= 1) {
        int t = (tid >= off) ? sh[tid - off] : 0;
        __syncthreads();
        sh[tid] += t;
        __syncthreads();
    }
    if (tid < nb) part[tid] = sh[tid] - v;
}

__global__ void scan_add(int* __restrict__ out, const int* __restrict__ part, int n) {
    int i = blockIdx.x * blockDim.x + threadIdx.x;
    if (i < n) out[i] += part[i >> 10];
}

__global__ void pass2_fill(const int* __restrict__ row, const int* __restrict__ col,
                           const float* __restrict__ w, const int* __restrict__ rowp,
                           const int* __restrict__ off, int2* __restrict__ meta, int E) {
    int e = blockIdx.x * blockDim.x + threadIdx.x;
    if (e < E) {
        int r = row[e];
        int idx = rowp[r] + off[e];
        int2 v;
        v.x = col[e];
        v.y = __float_as_int(w[e]);
        meta[idx] = v;
    }
}

__global__ void row_dinv(const int* __restrict__ rowp, const int2* __restrict__ meta,
                         float* __restrict__ dinv, int n) {
    int r = blockIdx.x * blockDim.x + threadIdx.x;
    if (r >= n) return;
    int e0 = rowp[r], e1 = rowp[r + 1];
    float s = 0.f;
    for (int e = e0; e < e1; ++e) s += __int_as_float(meta[e].y);
    dinv[r] = s > 0.f ? rsqrtf(s) : 0.f;
}

__global__ void scale_ev(const int* __restrict__ rowp, int2* __restrict__ meta,
                         const float* __restrict__ dinv, int n) {
    int r = blockIdx.x * blockDim.x + threadIdx.x;
    if (r >= n) return;
    int e0 = rowp[r], e1 = rowp[r + 1];
    float dr = dinv[r];
    for (int e = e0; e < e1; ++e) {
        int2 v = meta[e];
        float w = __int_as_float(v.y);
        v.y = __float_as_int(-dr * w * dinv[v.x]);
        meta[e] = v;
    }
}

// ---------------- fp32 -> bf16 bulk convert ----------------
__global__ void to_bf16(const float* __restrict__ in, unsigned* __restrict__ out, int n2) {
    int i = blockIdx.x * blockDim.x + threadIdx.x;  // 2 floats per thread
    if (i < n2) {
        float2 v = reinterpret_cast<const float2*>(in)[i];
        out[i] = pack2(v.x, v.y);
    }
}

// ---------------- W pre-pack into MFMA B-fragment layout ----------------
// W: fp32 [K][64] row-major. Wp: bf16, index ((kt*4+nt)*64+lane)*8 + j
//   = bf16( W[kt*32 + 8*(lane>>4) + j][nt*16 + (lane&15)] )
__global__ void wpack(const float* __restrict__ W, u16* __restrict__ Wp, int K) {
    int idx = blockIdx.x * blockDim.x + threadIdx.x;
    int tot = (K / 32) * 4 * 64;
    if (idx >= tot) return;
    int lane = idx & 63;
    int nt = (idx >> 6) & 3;
    int kt = idx >> 8;
    int krow = kt * 32 + (lane >> 4) * 8;
    int c = nt * 16 + (lane & 15);
    u16 tmp[8];
#pragma unroll
    for (int j = 0; j < 8; ++j) tmp[j] = f2bf(W[(size_t)(krow + j) * 64 + c]);
    *reinterpret_cast<uint4*>(Wp + (size_t)idx * 8) = *reinterpret_cast<const uint4*>(tmp);
}

// ---------------- SpMM (CSR), bf16 operand, fp32 accumulate ----------------
template <int F, bool AXPBY>
__global__ __launch_bounds__(256) void spmm_bf16(const int* __restrict__ rp,
                                                 const int2* __restrict__ meta,
                                                 const u16* __restrict__ x,
                                                 const u16* __restrict__ z,
                                                 u16* __restrict__ y, int n) {
    constexpr int TPR = F / 8;                 // threads per row (8 bf16 = uint4 each)
    constexpr int RPB = 256 / TPR;
    int r = blockIdx.x * RPB + threadIdx.x / TPR;
    if (r >= n) return;
    int f = (threadIdx.x % TPR) * 8;
    int e0 = rp[r], e1 = rp[r + 1];
    float acc[8] = {0.f, 0.f, 0.f, 0.f, 0.f, 0.f, 0.f, 0.f};
    for (int e = e0; e < e1; ++e) {
        int2 m = meta[e];
        float w = __int_as_float(m.y);
        uint4 xv = *reinterpret_cast<const uint4*>(x + (size_t)m.x * F + f);
        acc[0] += w * bflo(xv.x); acc[1] += w * bfhi(xv.x);
        acc[2] += w * bflo(xv.y); acc[3] += w * bfhi(xv.y);
        acc[4] += w * bflo(xv.z); acc[5] += w * bfhi(xv.z);
        acc[6] += w * bflo(xv.w); acc[7] += w * bfhi(xv.w);
    }
    if (AXPBY) {
        uint4 zv = *reinterpret_cast<const uint4*>(z + (size_t)r * F + f);
        acc[0] = 2.f * acc[0] - bflo(zv.x); acc[1] = 2.f * acc[1] - bfhi(zv.x);
        acc[2] = 2.f * acc[2] - bflo(zv.y); acc[3] = 2.f * acc[3] - bfhi(zv.y);
        acc[4] = 2.f * acc[4] - bflo(zv.z); acc[5] = 2.f * acc[5] - bfhi(zv.z);
        acc[6] = 2.f * acc[6] - bflo(zv.w); acc[7] = 2.f * acc[7] - bfhi(zv.w);
    }
    uint4 o;
    o.x = pack2(acc[0], acc[1]);
    o.y = pack2(acc[2], acc[3]);
    o.z = pack2(acc[4], acc[5]);
    o.w = pack2(acc[6], acc[7]);
    *reinterpret_cast<uint4*>(y + (size_t)r * F + f) = o;
}

// ---------------- MFMA 3-operand GEMM ----------------
// out[n][64] = act( [A0|A1|A2] @ W + bias ), W packed by wpack, all bf16 in,
// fp32 accumulate, bf16 out. Block = 4 waves; wave = 16 rows x 64 cols.
template <int F, bool RELU>
__global__ __launch_bounds__(256) void gemm3_mfma(const u16* __restrict__ A0,
                                                  const u16* __restrict__ A1,
                                                  const u16* __restrict__ A2,
                                                  const u16* __restrict__ Wp,
                                                  const float* __restrict__ bias,
                                                  u16* __restrict__ out, int n) {
    constexpr int KT = 3 * F / 32;
    int wave = threadIdx.x >> 6;
    int lane = threadIdx.x & 63;
    int r0 = blockIdx.x * 64 + wave * 16;
    int row = r0 + (lane & 15);
    int rowc = row < n ? row : n - 1;   // clamp; tail rows compute garbage, stores guarded
    int kofs = (lane >> 4) * 8;
    const u16* Ap[3] = {A0, A1, A2};
    f32x4 acc[4] = {{0.f, 0.f, 0.f, 0.f}, {0.f, 0.f, 0.f, 0.f},
                    {0.f, 0.f, 0.f, 0.f}, {0.f, 0.f, 0.f, 0.f}};
    for (int kt = 0; kt < KT; ++kt) {
        int k0 = kt * 32;
        const u16* A = Ap[k0 / F];
        int c0 = k0 % F;
        bf16x8 a = *reinterpret_cast<const bf16x8*>(A + (size_t)rowc * F + c0 + kofs);
        const u16* wb = Wp + (size_t)kt * 4 * 512 + (size_t)lane * 8;
#pragma unroll
        for (int nt = 0; nt < 4; ++nt) {
            bf16x8 b = *reinterpret_cast<const bf16x8*>(wb + nt * 512);
            acc[nt] = __builtin_amdgcn_mfma_f32_16x16x32_bf16(a, b, acc[nt], 0, 0, 0);
        }
    }
    int col = lane & 15;
    int rbase = (lane >> 4) * 2;  // pack 2 rows per uint: rows rbase*? -- see below
    // D mapping: row = 4*(lane>>4)+i, col = lane&15
#pragma unroll
    for (int nt = 0; nt < 4; ++nt) {
        float bb = bias[nt * 16 + col];
#pragma unroll
        for (int i = 0; i < 4; ++i) {
            int rr = r0 + (lane >> 4) * 4 + i;
            if (rr < n) {
                float v = acc[nt][i] + bb;
                if (RELU) v = fmaxf(v, 0.f);
                out[(size_t)rr * 64 + nt * 16 + col] = f2bf(v);
            }
        }
    }
    (void)rbase;
}

// ---------------- output layer: 3x(64->5) GEMV + log_softmax ----------------
__global__ __launch_bounds__(256) void out_layer(const u16* __restrict__ A0,
                                                 const u16* __restrict__ A1,
                                                 const u16* __restrict__ A2,
                                                 const float* __restrict__ W,    // [192][5]
                                                 const float* __restrict__ bias, // [5]
                                                 float* __restrict__ out, int n) {
    __shared__ float Ws[960];
    __shared__ float bs[8];
    int tid = threadIdx.x;
    for (int i = tid; i < 960; i += 256) Ws[i] = W[i];
    if (tid < 5) bs[tid] = bias[tid];
    __syncthreads();
    int nd = blockIdx.x * 256 + tid;
    if (nd >= n) return;
    float acc[5];
#pragma unroll
    for (int c = 0; c < 5; ++c) acc[c] = bs[c];
    const u16* Ap[3] = {A0, A1, A2};
#pragma unroll
    for (int m = 0; m < 3; ++m) {
        const uint4* a4 = reinterpret_cast<const uint4*>(Ap[m] + (size_t)nd * 64);
#pragma unroll
        for (int k8 = 0; k8 < 8; ++k8) {
            uint4 av = a4[k8];
            float a[8] = {bflo(av.x), bfhi(av.x), bflo(av.y), bfhi(av.y),
                          bflo(av.z), bfhi(av.z), bflo(av.w), bfhi(av.w)};
            int kb = (m * 64 + k8 * 8) * 5;
#pragma unroll
            for (int j = 0; j < 8; ++j)
#pragma unroll
                for (int c = 0; c < 5; ++c) acc[c] += a[j] * Ws[kb + 5 * j + c];
        }
    }
    float mx = acc[0];
#pragma unroll
    for (int c = 1; c < 5; ++c) mx = fmaxf(mx, acc[c]);
    float s = 0.f;
#pragma unroll
    for (int c = 0; c < 5; ++c) s += expf(acc[c] - mx);
    float l = logf(s);
#pragma unroll
    for (int c = 0; c < 5; ++c) out[(size_t)nd * 5 + c] = acc[c] - mx - l;
}

// ---------------- launch ----------------

static inline size_t alignup(size_t v) { return (v + 255) & ~(size_t)255; }

extern "C" void kernel_launch(void* const* d_in, const int* in_sizes, int n_in,
                              void* d_out, int out_size, void* d_ws, size_t ws_size,
                              hipStream_t stream) {
    const float* x  = (const float*)d_in[0];
    const int*   ei = (const int*)d_in[1];
    const float* ew = (const float*)d_in[2];
    const float* W1 = (const float*)d_in[3];
    const float* b1 = (const float*)d_in[4];
    const float* W3 = (const float*)d_in[5];
    const float* b3 = (const float*)d_in[6];
    const float* W4 = (const float*)d_in[7];
    const float* b4 = (const float*)d_in[8];
    float* out = (float*)d_out;

    const int D = 128, H = 64;
    const int N = in_sizes[0] / D;
    const int E = in_sizes[2];
    const int* row = ei;
    const int* col = ei + E;

    char* ws = (char*)d_ws;
    size_t off = 0;
    auto alloc = [&](size_t bytes) { size_t o = off; off += alignup(bytes); return o; };

    float* dinv = (float*)(ws + alloc((size_t)N * 4));
    int*   cnt  = (int*)  (ws + alloc((size_t)(N + 1) * 4));
    int*   rowp = (int*)  (ws + alloc((size_t)(N + 1) * 4));
    int*   part = (int*)  (ws + alloc(256 * 4));
    int2*  meta = (int2*) (ws + alloc((size_t)E * 8));
    u16*   xb   = (u16*)  (ws + alloc((size_t)N * D * 2));   // x in bf16
    u16*   bufA = (u16*)  (ws + alloc((size_t)N * D * 2));   // Tx1(L1); later Tx(L2)/Tx(L3)
    u16*   bufB = (u16*)  (ws + alloc((size_t)N * D * 2));   // Tx2(L1)
    u16*   h1   = (u16*)  (ws + alloc((size_t)N * H * 2));
    u16*   h2   = (u16*)  (ws + alloc((size_t)N * H * 2));
    u16*   Wp1  = (u16*)  (ws + alloc((size_t)3 * D * 64 * 2));  // packed W1 (K=384)
    u16*   Wp3  = (u16*)  (ws + alloc((size_t)3 * H * 64 * 2));  // packed W3 (K=192)

    // off[] is only live during CSR build, before bufA's first use -> alias it
    int* offBuf = (int*)bufA;

    u16* TxD  = bufA;                      // N*64 (layer2 Tx1)
    u16* TxE  = bufA + (size_t)N * H;      // N*64 (layer2 Tx2)
    u16* Tx1c = bufA;                      // layer3 Tx1
    u16* Tx2c = bufA + (size_t)N * H;      // layer3 Tx2

    dim3 blk(256);
    int gE = (E + 255) / 256;
    int gN = (N + 255) / 256;

    hipMemsetAsync(cnt, 0, (size_t)(N + 1) * 4, stream);

    pass1_count<<<gE, blk, 0, stream>>>(row, cnt, offBuf, E);

    int M = N + 1;
    int nb = (M + 1023) / 1024;
    scan_block<<<nb, blk, 0, stream>>>(cnt, rowp, part, M);
    scan_part_k<<<1, blk, 0, stream>>>(part, nb);
    scan_add<<<(M + 255) / 256, blk, 0, stream>>>(rowp, part, M);

    pass2_fill<<<gE, blk, 0, stream>>>(row, col, ew, rowp, offBuf, meta, E);
    row_dinv<<<gN, blk, 0, stream>>>(rowp, meta, dinv, N);
    scale_ev<<<gN, blk, 0, stream>>>(rowp, meta, dinv, N);

    int n2 = N * D / 2;
    to_bf16<<<(n2 + 255) / 256, blk, 0, stream>>>(x, (unsigned*)xb, n2);
    wpack<<<(3072 + 255) / 256, blk, 0, stream>>>(W1, Wp1, 3 * D);
    wpack<<<(1536 + 255) / 256, blk, 0, stream>>>(W3, Wp3, 3 * H);

    // ---- layer 1 (F=128 -> 64, relu) ----
    int g128 = (N + 15) / 16;  // 16 rows/block for F=128
    int g64  = (N + 31) / 32;  // 32 rows/block for F=64
    int gG   = (N + 63) / 64;
    spmm_bf16<128, false><<<g128, blk, 0, stream>>>(rowp, meta, xb, nullptr, bufA, N);
    spmm_bf16<128, true ><<<g128, blk, 0, stream>>>(rowp, meta, bufA, xb, bufB, N);
    gemm3_mfma<128, true><<<gG, blk, 0, stream>>>(xb, bufA, bufB, Wp1, b1, h1, N);

    // ---- layer 2 (F=64 -> 64, relu) ----
    spmm_bf16<64, false><<<g64, blk, 0, stream>>>(rowp, meta, h1, nullptr, TxD, N);
    spmm_bf16<64, true ><<<g64, blk, 0, stream>>>(rowp, meta, TxD, h1, TxE, N);
    gemm3_mfma<64, true><<<gG, blk, 0, stream>>>(h1, TxD, TxE, Wp3, b3, h2, N);

    // ---- layer 3 (F=64 -> 5) + log_softmax ----
    spmm_bf16<64, false><<<g64, blk, 0, stream>>>(rowp, meta, h2, nullptr, Tx1c, N);
    spmm_bf16<64, true ><<<g64, blk, 0, stream>>>(rowp, meta, Tx1c, h2, Tx2c, N);
    out_layer<<<gN, blk, 0, stream>>>(h2, Tx1c, Tx2c, W4, b4, out, N);
}

// Round 5
// 401.882 us; speedup vs baseline: 2.3318x; 1.3105x over previous
//
#include <hip/hip_runtime.h>
#include <cstdint>
#include <cstddef>

typedef unsigned short u16;
typedef __attribute__((ext_vector_type(8))) short bf16x8;
typedef __attribute__((ext_vector_type(4))) float f32x4;

// ---------------- bf16 helpers (RNE) ----------------
__device__ __forceinline__ float bflo(unsigned u) { return __uint_as_float(u << 16); }
__device__ __forceinline__ float bfhi(unsigned u) { return __uint_as_float(u & 0xFFFF0000u); }
__device__ __forceinline__ float bf2f(u16 v) { return __uint_as_float((unsigned)v << 16); }
__device__ __forceinline__ u16 f2bf(float f) {
    unsigned u = __float_as_uint(f);
    u += 0x7FFFu + ((u >> 16) & 1u);
    return (u16)(u >> 16);
}
__device__ __forceinline__ unsigned pack2(float a, float b) {
    return (unsigned)f2bf(a) | ((unsigned)f2bf(b) << 16);
}

// ---------------- CSR build (1 atomic per edge total) ----------------

__global__ void pass1_count(const int* __restrict__ row, int* __restrict__ cnt,
                            int* __restrict__ off, int E) {
    int e = blockIdx.x * blockDim.x + threadIdx.x;
    if (e < E) off[e] = atomicAdd(&cnt[row[e]], 1);
}

__global__ void scan_block(const int* __restrict__ in, int* __restrict__ out,
                           int* __restrict__ part, int n) {
    __shared__ int sh[256];
    int tid = threadIdx.x;
    int base = blockIdx.x * 1024 + tid * 4;
    int v[4];
#pragma unroll
    for (int j = 0; j < 4; ++j) v[j] = (base + j < n) ? in[base + j] : 0;
    int s = v[0] + v[1] + v[2] + v[3];
    sh[tid] = s;
    __syncthreads();
    for (int off = 1; off < 256; off <<= 1) {
        int t = (tid >= off) ? sh[tid - off] : 0;
        __syncthreads();
        sh[tid] += t;
        __syncthreads();
    }
    int run = sh[tid] - s;
#pragma unroll
    for (int j = 0; j < 4; ++j) {
        if (base + j < n) out[base + j] = run;
        run += v[j];
    }
    if (tid == 255) part[blockIdx.x] = sh[255];
}

__global__ void scan_part_k(int* __restrict__ part, int nb) {
    __shared__ int sh[256];
    int tid = threadIdx.x;
    int v = (tid < nb) ? part[tid] : 0;
    sh[tid] = v;
    __syncthreads();
    for (int off = 1; off < 256; off <<= 1) {
        int t = (tid >= off) ? sh[tid - off] : 0;
        __syncthreads();
        sh[tid] += t;
        __syncthreads();
    }
    if (tid < nb) part[tid] = sh[tid] - v;
}

__global__ void scan_add(int* __restrict__ out, const int* __restrict__ part, int n) {
    int i = blockIdx.x * blockDim.x + threadIdx.x;
    if (i < n) out[i] += part[i >> 10];
}

__global__ void pass2_fill(const int* __restrict__ row, const int* __restrict__ col,
                           const float* __restrict__ w, const int* __restrict__ rowp,
                           const int* __restrict__ off, int2* __restrict__ meta, int E) {
    int e = blockIdx.x * blockDim.x + threadIdx.x;
    if (e < E) {
        int r = row[e];
        int idx = rowp[r] + off[e];
        int2 v;
        v.x = col[e];
        v.y = __float_as_int(w[e]);
        meta[idx] = v;
    }
}

__global__ void row_dinv(const int* __restrict__ rowp, const int2* __restrict__ meta,
                         float* __restrict__ dinv, int n) {
    int r = blockIdx.x * blockDim.x + threadIdx.x;
    if (r >= n) return;
    int e0 = rowp[r], e1 = rowp[r + 1];
    float s = 0.f;
    for (int e = e0; e < e1; ++e) s += __int_as_float(meta[e].y);
    dinv[r] = s > 0.f ? rsqrtf(s) : 0.f;
}

__global__ void scale_ev(const int* __restrict__ rowp, int2* __restrict__ meta,
                         const float* __restrict__ dinv, int n) {
    int r = blockIdx.x * blockDim.x + threadIdx.x;
    if (r >= n) return;
    int e0 = rowp[r], e1 = rowp[r + 1];
    float dr = dinv[r];
    for (int e = e0; e < e1; ++e) {
        int2 v = meta[e];
        float w = __int_as_float(v.y);
        v.y = __float_as_int(-dr * w * dinv[v.x]);
        meta[e] = v;
    }
}

// ---------------- fp32 -> bf16 bulk convert ----------------
__global__ void to_bf16(const float* __restrict__ in, unsigned* __restrict__ out, int n2) {
    int i = blockIdx.x * blockDim.x + threadIdx.x;  // 2 floats per thread
    if (i < n2) {
        float2 v = reinterpret_cast<const float2*>(in)[i];
        out[i] = pack2(v.x, v.y);
    }
}

// ---------------- W packs into MFMA B-fragment layout ----------------
// B-frag: Wp[((kt*NT+nt)*64+lane)*8+j] = bf16( Wc[kt*32 + 8*(lane>>4)+j][nt*16+(lane&15)] )

// generic: W fp32 [K][64] contiguous (used for layer-2 W3, K=192, NT=4)
__global__ void wpack(const float* __restrict__ W, u16* __restrict__ Wp, int K) {
    int idx = blockIdx.x * blockDim.x + threadIdx.x;
    int tot = (K / 32) * 4 * 64;
    if (idx >= tot) return;
    int lane = idx & 63;
    int nt = (idx >> 6) & 3;
    int kt = idx >> 8;
    int krow = kt * 32 + (lane >> 4) * 8;
    int c = nt * 16 + (lane & 15);
    u16 tmp[8];
#pragma unroll
    for (int j = 0; j < 8; ++j) tmp[j] = f2bf(W[(size_t)(krow + j) * 64 + c]);
    *reinterpret_cast<uint4*>(Wp + (size_t)idx * 8) = *reinterpret_cast<const uint4*>(tmp);
}

// layer-1: W1 fp32 (3,128,64); Wc = [W0-W2 | W1 | W2], 128 x 192, NT=12, KT=4
__global__ void wpack_u(const float* __restrict__ W, u16* __restrict__ Wp) {
    int idx = blockIdx.x * blockDim.x + threadIdx.x;
    if (idx >= 4 * 12 * 64) return;
    int lane = idx & 63;
    int nt = (idx >> 6) % 12;
    int kt = idx / 768;
    int krow = kt * 32 + (lane >> 4) * 8;
    int c = nt * 16 + (lane & 15);
    u16 tmp[8];
#pragma unroll
    for (int j = 0; j < 8; ++j) {
        int k = krow + j;
        float v;
        if (c < 64)       v = W[(size_t)k * 64 + c] - W[2 * 8192 + (size_t)k * 64 + c];
        else if (c < 128) v = W[8192 + (size_t)k * 64 + (c - 64)];
        else              v = W[2 * 8192 + (size_t)k * 64 + (c - 128)];
        tmp[j] = f2bf(v);
    }
    *reinterpret_cast<uint4*>(Wp + (size_t)idx * 8) = *reinterpret_cast<const uint4*>(tmp);
}

// layer-3: W4 fp32 (3,64,5); Wc3 = 64 x 24 (3 panels of 8, 5 used each), NT=2, KT=2
__global__ void wpack_p(const float* __restrict__ W, u16* __restrict__ Wp) {
    int idx = blockIdx.x * blockDim.x + threadIdx.x;
    if (idx >= 2 * 2 * 64) return;
    int lane = idx & 63;
    int nt = (idx >> 6) & 1;
    int kt = idx >> 7;
    int krow = kt * 32 + (lane >> 4) * 8;
    int c = nt * 16 + (lane & 15);
    u16 tmp[8];
#pragma unroll
    for (int j = 0; j < 8; ++j) {
        int k = krow + j;
        float v = 0.f;
        if (c < 5)                 v = W[(size_t)k * 5 + c] - W[640 + (size_t)k * 5 + c];
        else if (c >= 8 && c < 13) v = W[320 + (size_t)k * 5 + (c - 8)];
        else if (c >= 16 && c < 21) v = W[640 + (size_t)k * 5 + (c - 16)];
        tmp[j] = f2bf(v);
    }
    *reinterpret_cast<uint4*>(Wp + (size_t)idx * 8) = *reinterpret_cast<const uint4*>(tmp);
}

// ---------------- SpMM (CSR) F=64, bf16, fp32 accumulate ----------------
// MODE 0: y = acc
// MODE 1: y = 2*acc + z
// MODE 2: y = 2*acc - z
// MODE 3: y = relu(acc + z + bias)
template <int MODE>
__global__ __launch_bounds__(256) void spmm64(const int* __restrict__ rp,
                                              const int2* __restrict__ meta,
                                              const u16* __restrict__ x,
                                              const u16* __restrict__ z,
                                              const float* __restrict__ bias,
                                              u16* __restrict__ y, int n) {
    int r = blockIdx.x * 32 + (threadIdx.x >> 3);
    if (r >= n) return;
    int f = (threadIdx.x & 7) * 8;
    int e0 = rp[r], e1 = rp[r + 1];
    float acc[8] = {0.f, 0.f, 0.f, 0.f, 0.f, 0.f, 0.f, 0.f};
    for (int e = e0; e < e1; ++e) {
        int2 m = meta[e];
        float w = __int_as_float(m.y);
        uint4 xv = *reinterpret_cast<const uint4*>(x + (size_t)m.x * 64 + f);
        acc[0] += w * bflo(xv.x); acc[1] += w * bfhi(xv.x);
        acc[2] += w * bflo(xv.y); acc[3] += w * bfhi(xv.y);
        acc[4] += w * bflo(xv.z); acc[5] += w * bfhi(xv.z);
        acc[6] += w * bflo(xv.w); acc[7] += w * bfhi(xv.w);
    }
    if (MODE == 1 || MODE == 2) {
        uint4 zv = *reinterpret_cast<const uint4*>(z + (size_t)r * 64 + f);
        float zz[8] = {bflo(zv.x), bfhi(zv.x), bflo(zv.y), bfhi(zv.y),
                       bflo(zv.z), bfhi(zv.z), bflo(zv.w), bfhi(zv.w)};
#pragma unroll
        for (int j = 0; j < 8; ++j)
            acc[j] = (MODE == 1) ? 2.f * acc[j] + zz[j] : 2.f * acc[j] - zz[j];
    } else if (MODE == 3) {
        uint4 zv = *reinterpret_cast<const uint4*>(z + (size_t)r * 64 + f);
        float zz[8] = {bflo(zv.x), bfhi(zv.x), bflo(zv.y), bfhi(zv.y),
                       bflo(zv.z), bfhi(zv.z), bflo(zv.w), bfhi(zv.w)};
        float4 bl = *reinterpret_cast<const float4*>(bias + f);
        float4 bh = *reinterpret_cast<const float4*>(bias + f + 4);
        float bb[8] = {bl.x, bl.y, bl.z, bl.w, bh.x, bh.y, bh.z, bh.w};
#pragma unroll
        for (int j = 0; j < 8; ++j) acc[j] = fmaxf(acc[j] + zz[j] + bb[j], 0.f);
    }
    uint4 o;
    o.x = pack2(acc[0], acc[1]);
    o.y = pack2(acc[2], acc[3]);
    o.z = pack2(acc[4], acc[5]);
    o.w = pack2(acc[6], acc[7]);
    *reinterpret_cast<uint4*>(y + (size_t)r * 64 + f) = o;
}

// ---------------- SpMM width-8 (padded 5), 4 threads per row ----------------
__device__ __forceinline__ void spmm8_acc(const int* rp, const int2* meta, const u16* x,
                                          int r, int t, float* acc) {
    int e0 = rp[r], e1 = rp[r + 1];
    for (int e = e0 + t; e < e1; e += 4) {
        int2 m = meta[e];
        float w = __int_as_float(m.y);
        uint4 xv = *reinterpret_cast<const uint4*>(x + (size_t)m.x * 8);
        acc[0] += w * bflo(xv.x); acc[1] += w * bfhi(xv.x);
        acc[2] += w * bflo(xv.y); acc[3] += w * bfhi(xv.y);
        acc[4] += w * bflo(xv.z); acc[5] += w * bfhi(xv.z);
        acc[6] += w * bflo(xv.w); acc[7] += w * bfhi(xv.w);
    }
#pragma unroll
    for (int j = 0; j < 8; ++j)
        acc[j] += __shfl_xor(acc[j], 1) ;
#pragma unroll
    for (int j = 0; j < 8; ++j)
        acc[j] += __shfl_xor(acc[j], 2);
}

// w5 = 2*L*p2 + p1
__global__ __launch_bounds__(256) void spmm8_p2(const int* __restrict__ rp,
                                                const int2* __restrict__ meta,
                                                const u16* __restrict__ x,
                                                const u16* __restrict__ z,
                                                u16* __restrict__ y, int n) {
    int r = blockIdx.x * 64 + (threadIdx.x >> 2);
    if (r >= n) return;
    int t = threadIdx.x & 3;
    float acc[8] = {0.f, 0.f, 0.f, 0.f, 0.f, 0.f, 0.f, 0.f};
    spmm8_acc(rp, meta, x, r, t, acc);
    if (t == 0) {
        uint4 zv = *reinterpret_cast<const uint4*>(z + (size_t)r * 8);
        float zz[8] = {bflo(zv.x), bfhi(zv.x), bflo(zv.y), bfhi(zv.y),
                       bflo(zv.z), bfhi(zv.z), bflo(zv.w), bfhi(zv.w)};
        uint4 o;
        o.x = pack2(2.f * acc[0] + zz[0], 2.f * acc[1] + zz[1]);
        o.y = pack2(2.f * acc[2] + zz[2], 2.f * acc[3] + zz[3]);
        o.z = pack2(2.f * acc[4] + zz[4], 2.f * acc[5] + zz[5]);
        o.w = pack2(2.f * acc[6] + zz[6], 2.f * acc[7] + zz[7]);
        *reinterpret_cast<uint4*>(y + (size_t)r * 8) = o;
    }
}

// out = log_softmax(L*w5 + p0 + b4) over 5 classes, fp32 out
__global__ __launch_bounds__(256) void spmm8_lsm(const int* __restrict__ rp,
                                                 const int2* __restrict__ meta,
                                                 const u16* __restrict__ x,
                                                 const u16* __restrict__ z,
                                                 const float* __restrict__ bias,
                                                 float* __restrict__ out, int n) {
    int r = blockIdx.x * 64 + (threadIdx.x >> 2);
    if (r >= n) return;
    int t = threadIdx.x & 3;
    float acc[8] = {0.f, 0.f, 0.f, 0.f, 0.f, 0.f, 0.f, 0.f};
    spmm8_acc(rp, meta, x, r, t, acc);
    if (t == 0) {
        uint4 zv = *reinterpret_cast<const uint4*>(z + (size_t)r * 8);
        float zz[8] = {bflo(zv.x), bfhi(zv.x), bflo(zv.y), bfhi(zv.y),
                       bflo(zv.z), bfhi(zv.z), bflo(zv.w), bfhi(zv.w)};
        float val[5];
#pragma unroll
        for (int j = 0; j < 5; ++j) val[j] = acc[j] + zz[j] + bias[j];
        float mx = val[0];
#pragma unroll
        for (int j = 1; j < 5; ++j) mx = fmaxf(mx, val[j]);
        float s = 0.f;
#pragma unroll
        for (int j = 0; j < 5; ++j) s += expf(val[j] - mx);
        float l = logf(s);
#pragma unroll
        for (int j = 0; j < 5; ++j) out[(size_t)r * 5 + j] = val[j] - mx - l;
    }
}

// ---------------- MFMA GEMMs ----------------

// layer 1 projection: [u0|u1|u2] = xb @ Wc (128 x 192), bf16 out into 3 bufs
__global__ __launch_bounds__(256) void gemm_u(const u16* __restrict__ A,
                                              const u16* __restrict__ Wp,
                                              u16* __restrict__ u0, u16* __restrict__ u1,
                                              u16* __restrict__ u2, int n) {
    int wave = threadIdx.x >> 6;
    int lane = threadIdx.x & 63;
    int r0 = blockIdx.x * 64 + wave * 16;
    int row = r0 + (lane & 15);
    int rowc = row < n ? row : n - 1;
    int kofs = (lane >> 4) * 8;
    f32x4 acc[12] = {};
    for (int kt = 0; kt < 4; ++kt) {
        bf16x8 a = *reinterpret_cast<const bf16x8*>(A + (size_t)rowc * 128 + kt * 32 + kofs);
        const u16* wb = Wp + (size_t)kt * 12 * 512 + (size_t)lane * 8;
#pragma unroll
        for (int nt = 0; nt < 12; ++nt) {
            bf16x8 b = *reinterpret_cast<const bf16x8*>(wb + nt * 512);
            acc[nt] = __builtin_amdgcn_mfma_f32_16x16x32_bf16(a, b, acc[nt], 0, 0, 0);
        }
    }
    int col = lane & 15;
    u16* U[3] = {u0, u1, u2};
#pragma unroll
    for (int nt = 0; nt < 12; ++nt) {
        u16* dst = U[nt >> 2];
        int cc = (nt & 3) * 16 + col;
#pragma unroll
        for (int i = 0; i < 4; ++i) {
            int rr = r0 + (lane >> 4) * 4 + i;
            if (rr < n) dst[(size_t)rr * 64 + cc] = f2bf(acc[nt][i]);
        }
    }
}

// layer 2: out = relu([A0|A1|A2] @ W + bias), K=192
__global__ __launch_bounds__(256) void gemm3_mfma(const u16* __restrict__ A0,
                                                  const u16* __restrict__ A1,
                                                  const u16* __restrict__ A2,
                                                  const u16* __restrict__ Wp,
                                                  const float* __restrict__ bias,
                                                  u16* __restrict__ out, int n) {
    int wave = threadIdx.x >> 6;
    int lane = threadIdx.x & 63;
    int r0 = blockIdx.x * 64 + wave * 16;
    int row = r0 + (lane & 15);
    int rowc = row < n ? row : n - 1;
    int kofs = (lane >> 4) * 8;
    const u16* Ap[3] = {A0, A1, A2};
    f32x4 acc[4] = {};
    for (int kt = 0; kt < 6; ++kt) {
        const u16* Asrc = Ap[kt >> 1];
        int c0 = (kt & 1) * 32;
        bf16x8 a = *reinterpret_cast<const bf16x8*>(Asrc + (size_t)rowc * 64 + c0 + kofs);
        const u16* wb = Wp + (size_t)kt * 4 * 512 + (size_t)lane * 8;
#pragma unroll
        for (int nt = 0; nt < 4; ++nt) {
            bf16x8 b = *reinterpret_cast<const bf16x8*>(wb + nt * 512);
            acc[nt] = __builtin_amdgcn_mfma_f32_16x16x32_bf16(a, b, acc[nt], 0, 0, 0);
        }
    }
    int col = lane & 15;
#pragma unroll
    for (int nt = 0; nt < 4; ++nt) {
        float bb = bias[nt * 16 + col];
#pragma unroll
        for (int i = 0; i < 4; ++i) {
            int rr = r0 + (lane >> 4) * 4 + i;
            if (rr < n) {
                float v = fmaxf(acc[nt][i] + bb, 0.f);
                out[(size_t)rr * 64 + nt * 16 + col] = f2bf(v);
            }
        }
    }
}

// layer 3 projection: [p0|p1|p2](each N x 8) = h2 @ Wc3 (64 x 24)
__global__ __launch_bounds__(256) void gemm_proj(const u16* __restrict__ A,
                                                 const u16* __restrict__ Wp,
                                                 u16* __restrict__ p0, u16* __restrict__ p1,
                                                 u16* __restrict__ p2, int n) {
    int wave = threadIdx.x >> 6;
    int lane = threadIdx.x & 63;
    int r0 = blockIdx.x * 64 + wave * 16;
    int row = r0 + (lane & 15);
    int rowc = row < n ? row : n - 1;
    int kofs = (lane >> 4) * 8;
    f32x4 acc[2] = {};
    for (int kt = 0; kt < 2; ++kt) {
        bf16x8 a = *reinterpret_cast<const bf16x8*>(A + (size_t)rowc * 64 + kt * 32 + kofs);
        const u16* wb = Wp + (size_t)kt * 2 * 512 + (size_t)lane * 8;
#pragma unroll
        for (int nt = 0; nt < 2; ++nt) {
            bf16x8 b = *reinterpret_cast<const bf16x8*>(wb + nt * 512);
            acc[nt] = __builtin_amdgcn_mfma_f32_16x16x32_bf16(a, b, acc[nt], 0, 0, 0);
        }
    }
    int col = lane & 15;
    u16* P[3] = {p0, p1, p2};
#pragma unroll
    for (int nt = 0; nt < 2; ++nt) {
        int c = nt * 16 + col;
        if (c < 24) {
            u16* dst = P[c >> 3];
            int j = c & 7;
#pragma unroll
            for (int i = 0; i < 4; ++i) {
                int rr = r0 + (lane >> 4) * 4 + i;
                if (rr < n) dst[(size_t)rr * 8 + j] = f2bf(acc[nt][i]);
            }
        }
    }
}

// ---------------- launch ----------------

static inline size_t alignup(size_t v) { return (v + 255) & ~(size_t)255; }

extern "C" void kernel_launch(void* const* d_in, const int* in_sizes, int n_in,
                              void* d_out, int out_size, void* d_ws, size_t ws_size,
                              hipStream_t stream) {
    const float* x  = (const float*)d_in[0];
    const int*   ei = (const int*)d_in[1];
    const float* ew = (const float*)d_in[2];
    const float* W1 = (const float*)d_in[3];
    const float* b1 = (const float*)d_in[4];
    const float* W3 = (const float*)d_in[5];
    const float* b3 = (const float*)d_in[6];
    const float* W4 = (const float*)d_in[7];
    const float* b4 = (const float*)d_in[8];
    float* out = (float*)d_out;

    const int D = 128, H = 64;
    const int N = in_sizes[0] / D;
    const int E = in_sizes[2];
    const int* row = ei;
    const int* col = ei + E;

    char* ws = (char*)d_ws;
    size_t off = 0;
    auto alloc = [&](size_t bytes) { size_t o = off; off += alignup(bytes); return o; };

    float* dinv = (float*)(ws + alloc((size_t)N * 4));
    int*   cnt  = (int*)  (ws + alloc((size_t)(N + 1) * 4));
    int*   rowp = (int*)  (ws + alloc((size_t)(N + 1) * 4));
    int*   part = (int*)  (ws + alloc(256 * 4));
    int2*  meta = (int2*) (ws + alloc((size_t)E * 8));
    u16*   xb   = (u16*)  (ws + alloc((size_t)N * D * 2));   // x in bf16
    u16*   A    = (u16*)  (ws + alloc((size_t)N * H * 2));
    u16*   B    = (u16*)  (ws + alloc((size_t)N * H * 2));
    u16*   C    = (u16*)  (ws + alloc((size_t)N * H * 2));
    u16*   Dd   = (u16*)  (ws + alloc((size_t)N * H * 2));
    u16*   P0   = (u16*)  (ws + alloc((size_t)N * 8 * 2));
    u16*   P1   = (u16*)  (ws + alloc((size_t)N * 8 * 2));
    u16*   P2   = (u16*)  (ws + alloc((size_t)N * 8 * 2));
    u16*   P3   = (u16*)  (ws + alloc((size_t)N * 8 * 2));
    u16*   Wpu  = (u16*)  (ws + alloc((size_t)4 * 12 * 512 * 2));  // layer-1 pack
    u16*   Wp3  = (u16*)  (ws + alloc((size_t)6 * 4 * 512 * 2));   // layer-2 pack
    u16*   Wpp  = (u16*)  (ws + alloc((size_t)2 * 2 * 512 * 2));   // layer-3 pack

    // off[] only live during CSR build; A+B (25.6MB > 6.4MB) first written later
    int* offBuf = (int*)A;

    dim3 blk(256);
    int gE = (E + 255) / 256;
    int gN = (N + 255) / 256;

    hipMemsetAsync(cnt, 0, (size_t)(N + 1) * 4, stream);

    pass1_count<<<gE, blk, 0, stream>>>(row, cnt, offBuf, E);

    int M = N + 1;
    int nb = (M + 1023) / 1024;
    scan_block<<<nb, blk, 0, stream>>>(cnt, rowp, part, M);
    scan_part_k<<<1, blk, 0, stream>>>(part, nb);
    scan_add<<<(M + 255) / 256, blk, 0, stream>>>(rowp, part, M);

    pass2_fill<<<gE, blk, 0, stream>>>(row, col, ew, rowp, offBuf, meta, E);
    row_dinv<<<gN, blk, 0, stream>>>(rowp, meta, dinv, N);
    scale_ev<<<gN, blk, 0, stream>>>(rowp, meta, dinv, N);

    int n2 = N * D / 2;
    to_bf16<<<(n2 + 255) / 256, blk, 0, stream>>>(x, (unsigned*)xb, n2);
    wpack_u<<<(3072 + 255) / 256, blk, 0, stream>>>(W1, Wpu);
    wpack<<<(6144 + 255) / 256, blk, 0, stream>>>(W3, Wp3, 3 * H);
    wpack_p<<<1, blk, 0, stream>>>(W4, Wpp);

    int g64 = (N + 31) / 32;
    int gG  = (N + 63) / 64;
    int g8  = (N + 63) / 64;

    // ---- layer 1: u=[u0|u1|u2]=x@Wc ; w=2*L*u2+u1 ; h1=relu(L*w+u0+b1) ----
    gemm_u<<<gG, blk, 0, stream>>>(xb, Wpu, A, B, C, N);              // u0=A u1=B u2=C
    spmm64<1><<<g64, blk, 0, stream>>>(rowp, meta, C, B, nullptr, Dd, N);  // w -> Dd
    spmm64<3><<<g64, blk, 0, stream>>>(rowp, meta, Dd, A, b1, B, N);       // h1 -> B

    // ---- layer 2: Ty1=L*h1 ; Ty2=2*L*Ty1-h1 ; h2=relu([h1|Ty1|Ty2]@W3+b3) ----
    spmm64<0><<<g64, blk, 0, stream>>>(rowp, meta, B, nullptr, nullptr, C, N);  // Ty1 -> C
    spmm64<2><<<g64, blk, 0, stream>>>(rowp, meta, C, B, nullptr, A, N);        // Ty2 -> A
    gemm3_mfma<<<gG, blk, 0, stream>>>(B, C, A, Wp3, b3, Dd, N);                // h2 -> Dd

    // ---- layer 3: p=[p0|p1|p2]=h2@Wc3 ; w5=2*L*p2+p1 ; out=lsm(L*w5+p0+b4) ----
    gemm_proj<<<gG, blk, 0, stream>>>(Dd, Wpp, P0, P1, P2, N);
    spmm8_p2<<<g8, blk, 0, stream>>>(rowp, meta, P2, P1, P3, N);
    spmm8_lsm<<<g8, blk, 0, stream>>>(rowp, meta, P3, P0, b4, out, N);
}

// Round 6
// 346.989 us; speedup vs baseline: 2.7006x; 1.1582x over previous
//
#include <hip/hip_runtime.h>
#include <cstdint>
#include <cstddef>

typedef unsigned short u16;
typedef __attribute__((ext_vector_type(8))) short bf16x8;
typedef __attribute__((ext_vector_type(4))) float f32x4;

#define PB 1024   // partition blocks for binA/binC
#define MAXB 1024 // max coarse bins (N <= 131072)

// ---------------- bf16 helpers (RNE) ----------------
__device__ __forceinline__ float bflo(unsigned u) { return __uint_as_float(u << 16); }
__device__ __forceinline__ float bfhi(unsigned u) { return __uint_as_float(u & 0xFFFF0000u); }
__device__ __forceinline__ u16 f2bf(float f) {
    unsigned u = __float_as_uint(f);
    u += 0x7FFFu + ((u >> 16) & 1u);
    return (u16)(u >> 16);
}
__device__ __forceinline__ unsigned pack2(float a, float b) {
    return (unsigned)f2bf(a) | ((unsigned)f2bf(b) << 16);
}

// ================= CSR build: binned, zero global atomics =================

// pass A: per-block coarse-bin histogram (bin = row>>7)
__global__ __launch_bounds__(256) void binA(const int* __restrict__ row, int* __restrict__ P,
                                            int E, int NB, int EB) {
    __shared__ int hist[MAXB];
    int b = blockIdx.x;
    for (int i = threadIdx.x; i < NB; i += 256) hist[i] = 0;
    __syncthreads();
    int e0 = b * EB, e1 = min(E, e0 + EB);
    for (int e = e0 + threadIdx.x; e < e1; e += 256)
        atomicAdd(&hist[row[e] >> 7], 1);
    __syncthreads();
    for (int i = threadIdx.x; i < NB; i += 256) P[(size_t)i * PB + b] = hist[i];
}

// pass B1: per-bin exclusive scan over the PB=1024 block-partials; emit bin totals
__global__ __launch_bounds__(256) void binB1(int* __restrict__ P, int* __restrict__ bintot) {
    __shared__ int sh[256];
    int* p = P + (size_t)blockIdx.x * PB;
    int tid = threadIdx.x;
    int base = tid * 4;
    int v[4];
#pragma unroll
    for (int j = 0; j < 4; ++j) v[j] = p[base + j];
    int s = v[0] + v[1] + v[2] + v[3];
    sh[tid] = s;
    __syncthreads();
    for (int off = 1; off < 256; off <<= 1) {
        int t = (tid >= off) ? sh[tid - off] : 0;
        __syncthreads();
        sh[tid] += t;
        __syncthreads();
    }
    int run = sh[tid] - s;
#pragma unroll
    for (int j = 0; j < 4; ++j) { p[base + j] = run; run += v[j]; }
    if (tid == 255) bintot[blockIdx.x] = sh[255];
}

// pass B2: single-block exclusive scan over bin totals -> bstart[NB+1]
__global__ __launch_bounds__(256) void binB2(const int* __restrict__ bintot,
                                             int* __restrict__ bstart, int NB) {
    __shared__ int sh[256];
    int tid = threadIdx.x;
    int base = tid * 4;
    int v[4];
#pragma unroll
    for (int j = 0; j < 4; ++j) v[j] = (base + j < NB) ? bintot[base + j] : 0;
    int s = v[0] + v[1] + v[2] + v[3];
    sh[tid] = s;
    __syncthreads();
    for (int off = 1; off < 256; off <<= 1) {
        int t = (tid >= off) ? sh[tid - off] : 0;
        __syncthreads();
        sh[tid] += t;
        __syncthreads();
    }
    int run = sh[tid] - s;
#pragma unroll
    for (int j = 0; j < 4; ++j) {
        if (base + j < NB) bstart[base + j] = run;
        run += v[j];
    }
    if (tid == 255) bstart[NB] = sh[255];
}

// pass C: scatter edges into bin-contiguous records {col | rowlo<<17, w}
__global__ __launch_bounds__(256) void binC(const int* __restrict__ row, const int* __restrict__ col,
                                            const float* __restrict__ w, const int* __restrict__ P,
                                            const int* __restrict__ bstart, int2* __restrict__ rec,
                                            int E, int NB, int EB) {
    __shared__ int cur[MAXB];
    int b = blockIdx.x;
    for (int i = threadIdx.x; i < NB; i += 256)
        cur[i] = bstart[i] + P[(size_t)i * PB + b];
    __syncthreads();
    int e0 = b * EB, e1 = min(E, e0 + EB);
    for (int e = e0 + threadIdx.x; e < e1; e += 256) {
        int r = row[e];
        int bin = r >> 7;
        int slot = atomicAdd(&cur[bin], 1);
        rec[slot] = make_int2(col[e] | ((r & 127) << 17), __float_as_int(w[e]));
    }
}

// pass D: per-bin fine CSR: rowp, dinv, and final meta placement
__global__ __launch_bounds__(256) void binD(const int2* __restrict__ rec,
                                            const int* __restrict__ bstart,
                                            int2* __restrict__ meta, int* __restrict__ rowp,
                                            float* __restrict__ dinv, int N, int NB) {
    __shared__ int cnt[128], st[128], cur[128];
    __shared__ float deg[128];
    int bin = blockIdx.x;
    int tid = threadIdx.x;
    if (tid < 128) { cnt[tid] = 0; deg[tid] = 0.f; }
    __syncthreads();
    int e0 = bstart[bin], e1 = bstart[bin + 1];
    for (int e = e0 + tid; e < e1; e += 256) {
        int2 v = rec[e];
        int rl = (v.x >> 17) & 127;
        atomicAdd(&cnt[rl], 1);
        atomicAdd(&deg[rl], __int_as_float(v.y));
    }
    __syncthreads();
    if (tid < 128) st[tid] = cnt[tid];
    __syncthreads();
    for (int off = 1; off < 128; off <<= 1) {
        int t = (tid >= off && tid < 128) ? st[tid - off] : 0;
        __syncthreads();
        if (tid < 128) st[tid] += t;
        __syncthreads();
    }
    int rows = min(128, N - bin * 128);
    if (tid < 128) {
        int excl = st[tid] - cnt[tid];
        cur[tid] = e0 + excl;
        if (tid < rows) {
            rowp[bin * 128 + tid] = e0 + excl;
            float d = deg[tid];
            dinv[bin * 128 + tid] = d > 0.f ? rsqrtf(d) : 0.f;
        }
    }
    if (bin == NB - 1 && tid == 0) rowp[N] = e1;
    __syncthreads();
    for (int e = e0 + tid; e < e1; e += 256) {
        int2 v = rec[e];
        int rl = (v.x >> 17) & 127;
        int slot = atomicAdd(&cur[rl], 1);
        meta[slot] = make_int2(v.x & 0x1FFFF, v.y);
    }
}

// per-row: ev[e] = -dinv[r] * w * dinv[col[e]] in place
__global__ void scale_ev(const int* __restrict__ rowp, int2* __restrict__ meta,
                         const float* __restrict__ dinv, int n) {
    int r = blockIdx.x * blockDim.x + threadIdx.x;
    if (r >= n) return;
    int e0 = rowp[r], e1 = rowp[r + 1];
    float dr = dinv[r];
    for (int e = e0; e < e1; ++e) {
        int2 v = meta[e];
        float w = __int_as_float(v.y);
        v.y = __float_as_int(-dr * w * dinv[v.x]);
        meta[e] = v;
    }
}

// ---------------- fp32 -> bf16 bulk convert ----------------
__global__ void to_bf16(const float* __restrict__ in, unsigned* __restrict__ out, int n2) {
    int i = blockIdx.x * blockDim.x + threadIdx.x;  // 2 floats per thread
    if (i < n2) {
        float2 v = reinterpret_cast<const float2*>(in)[i];
        out[i] = pack2(v.x, v.y);
    }
}

// ---------------- W packs into MFMA B-fragment layout (fused) ----------------
// B-frag: Wp[((kt*NT+nt)*64+lane)*8+j] = bf16( Wc[kt*32 + 8*(lane>>4)+j][nt*16+(lane&15)] )
__global__ void wpack_all(const float* __restrict__ W1, const float* __restrict__ W3,
                          const float* __restrict__ W4, u16* __restrict__ Wpu,
                          u16* __restrict__ Wp3, u16* __restrict__ Wpp) {
    int gi = blockIdx.x * blockDim.x + threadIdx.x;
    if (gi < 3072) {
        // layer-1: Wc = [W1_0-W1_2 | W1_1 | W1_2], 128 x 192, NT=12, KT=4
        int idx = gi;
        int lane = idx & 63;
        int nt = (idx >> 6) % 12;
        int kt = idx / 768;
        int krow = kt * 32 + (lane >> 4) * 8;
        int c = nt * 16 + (lane & 15);
        u16 tmp[8];
#pragma unroll
        for (int j = 0; j < 8; ++j) {
            int k = krow + j;
            float v;
            if (c < 64)       v = W1[(size_t)k * 64 + c] - W1[2 * 8192 + (size_t)k * 64 + c];
            else if (c < 128) v = W1[8192 + (size_t)k * 64 + (c - 64)];
            else              v = W1[2 * 8192 + (size_t)k * 64 + (c - 128)];
            tmp[j] = f2bf(v);
        }
        *reinterpret_cast<uint4*>(Wpu + (size_t)idx * 8) = *reinterpret_cast<const uint4*>(tmp);
    } else if (gi < 3072 + 1536) {
        // layer-2: W3 as [192][64], NT=4, KT=6
        int idx = gi - 3072;
        int lane = idx & 63;
        int nt = (idx >> 6) & 3;
        int kt = idx >> 8;
        int krow = kt * 32 + (lane >> 4) * 8;
        int c = nt * 16 + (lane & 15);
        u16 tmp[8];
#pragma unroll
        for (int j = 0; j < 8; ++j) tmp[j] = f2bf(W3[(size_t)(krow + j) * 64 + c]);
        *reinterpret_cast<uint4*>(Wp3 + (size_t)idx * 8) = *reinterpret_cast<const uint4*>(tmp);
    } else if (gi < 3072 + 1536 + 256) {
        // layer-3: Wc3 = 64 x 24 (3 panels of 8, 5 used), NT=2, KT=2
        int idx = gi - (3072 + 1536);
        int lane = idx & 63;
        int nt = (idx >> 6) & 1;
        int kt = idx >> 7;
        int krow = kt * 32 + (lane >> 4) * 8;
        int c = nt * 16 + (lane & 15);
        u16 tmp[8];
#pragma unroll
        for (int j = 0; j < 8; ++j) {
            int k = krow + j;
            float v = 0.f;
            if (c < 5)                  v = W4[(size_t)k * 5 + c] - W4[640 + (size_t)k * 5 + c];
            else if (c >= 8 && c < 13)  v = W4[320 + (size_t)k * 5 + (c - 8)];
            else if (c >= 16 && c < 21) v = W4[640 + (size_t)k * 5 + (c - 16)];
            tmp[j] = f2bf(v);
        }
        *reinterpret_cast<uint4*>(Wpp + (size_t)idx * 8) = *reinterpret_cast<const uint4*>(tmp);
    }
}

// ---------------- SpMM (CSR) F=64, bf16, fp32 accumulate ----------------
// MODE 0: y = acc ; 1: y = 2*acc + z ; 2: y = 2*acc - z ; 3: y = relu(acc + z + bias)
template <int MODE>
__global__ __launch_bounds__(256) void spmm64(const int* __restrict__ rp,
                                              const int2* __restrict__ meta,
                                              const u16* __restrict__ x,
                                              const u16* __restrict__ z,
                                              const float* __restrict__ bias,
                                              u16* __restrict__ y, int n) {
    int r = blockIdx.x * 32 + (threadIdx.x >> 3);
    if (r >= n) return;
    int f = (threadIdx.x & 7) * 8;
    int e0 = rp[r], e1 = rp[r + 1];
    float acc[8] = {0.f, 0.f, 0.f, 0.f, 0.f, 0.f, 0.f, 0.f};
    for (int e = e0; e < e1; ++e) {
        int2 m = meta[e];
        float w = __int_as_float(m.y);
        uint4 xv = *reinterpret_cast<const uint4*>(x + (size_t)m.x * 64 + f);
        acc[0] += w * bflo(xv.x); acc[1] += w * bfhi(xv.x);
        acc[2] += w * bflo(xv.y); acc[3] += w * bfhi(xv.y);
        acc[4] += w * bflo(xv.z); acc[5] += w * bfhi(xv.z);
        acc[6] += w * bflo(xv.w); acc[7] += w * bfhi(xv.w);
    }
    if (MODE == 1 || MODE == 2) {
        uint4 zv = *reinterpret_cast<const uint4*>(z + (size_t)r * 64 + f);
        float zz[8] = {bflo(zv.x), bfhi(zv.x), bflo(zv.y), bfhi(zv.y),
                       bflo(zv.z), bfhi(zv.z), bflo(zv.w), bfhi(zv.w)};
#pragma unroll
        for (int j = 0; j < 8; ++j)
            acc[j] = (MODE == 1) ? 2.f * acc[j] + zz[j] : 2.f * acc[j] - zz[j];
    } else if (MODE == 3) {
        uint4 zv = *reinterpret_cast<const uint4*>(z + (size_t)r * 64 + f);
        float zz[8] = {bflo(zv.x), bfhi(zv.x), bflo(zv.y), bfhi(zv.y),
                       bflo(zv.z), bfhi(zv.z), bflo(zv.w), bfhi(zv.w)};
        float4 bl = *reinterpret_cast<const float4*>(bias + f);
        float4 bh = *reinterpret_cast<const float4*>(bias + f + 4);
        float bb[8] = {bl.x, bl.y, bl.z, bl.w, bh.x, bh.y, bh.z, bh.w};
#pragma unroll
        for (int j = 0; j < 8; ++j) acc[j] = fmaxf(acc[j] + zz[j] + bb[j], 0.f);
    }
    uint4 o;
    o.x = pack2(acc[0], acc[1]);
    o.y = pack2(acc[2], acc[3]);
    o.z = pack2(acc[4], acc[5]);
    o.w = pack2(acc[6], acc[7]);
    *reinterpret_cast<uint4*>(y + (size_t)r * 64 + f) = o;
}

// ---------------- SpMM width-8 (padded 5), 4 threads per row ----------------
__device__ __forceinline__ void spmm8_acc(const int* rp, const int2* meta, const u16* x,
                                          int r, int t, float* acc) {
    int e0 = rp[r], e1 = rp[r + 1];
    for (int e = e0 + t; e < e1; e += 4) {
        int2 m = meta[e];
        float w = __int_as_float(m.y);
        uint4 xv = *reinterpret_cast<const uint4*>(x + (size_t)m.x * 8);
        acc[0] += w * bflo(xv.x); acc[1] += w * bfhi(xv.x);
        acc[2] += w * bflo(xv.y); acc[3] += w * bfhi(xv.y);
        acc[4] += w * bflo(xv.z); acc[5] += w * bfhi(xv.z);
        acc[6] += w * bflo(xv.w); acc[7] += w * bfhi(xv.w);
    }
#pragma unroll
    for (int j = 0; j < 8; ++j) acc[j] += __shfl_xor(acc[j], 1);
#pragma unroll
    for (int j = 0; j < 8; ++j) acc[j] += __shfl_xor(acc[j], 2);
}

// w5 = 2*L*p2 + p1
__global__ __launch_bounds__(256) void spmm8_p2(const int* __restrict__ rp,
                                                const int2* __restrict__ meta,
                                                const u16* __restrict__ x,
                                                const u16* __restrict__ z,
                                                u16* __restrict__ y, int n) {
    int r = blockIdx.x * 64 + (threadIdx.x >> 2);
    if (r >= n) return;
    int t = threadIdx.x & 3;
    float acc[8] = {0.f, 0.f, 0.f, 0.f, 0.f, 0.f, 0.f, 0.f};
    spmm8_acc(rp, meta, x, r, t, acc);
    if (t == 0) {
        uint4 zv = *reinterpret_cast<const uint4*>(z + (size_t)r * 8);
        float zz[8] = {bflo(zv.x), bfhi(zv.x), bflo(zv.y), bfhi(zv.y),
                       bflo(zv.z), bfhi(zv.z), bflo(zv.w), bfhi(zv.w)};
        uint4 o;
        o.x = pack2(2.f * acc[0] + zz[0], 2.f * acc[1] + zz[1]);
        o.y = pack2(2.f * acc[2] + zz[2], 2.f * acc[3] + zz[3]);
        o.z = pack2(2.f * acc[4] + zz[4], 2.f * acc[5] + zz[5]);
        o.w = pack2(2.f * acc[6] + zz[6], 2.f * acc[7] + zz[7]);
        *reinterpret_cast<uint4*>(y + (size_t)r * 8) = o;
    }
}

// out = log_softmax(L*w5 + p0 + b4) over 5 classes, fp32 out
__global__ __launch_bounds__(256) void spmm8_lsm(const int* __restrict__ rp,
                                                 const int2* __restrict__ meta,
                                                 const u16* __restrict__ x,
                                                 const u16* __restrict__ z,
                                                 const float* __restrict__ bias,
                                                 float* __restrict__ out, int n) {
    int r = blockIdx.x * 64 + (threadIdx.x >> 2);
    if (r >= n) return;
    int t = threadIdx.x & 3;
    float acc[8] = {0.f, 0.f, 0.f, 0.f, 0.f, 0.f, 0.f, 0.f};
    spmm8_acc(rp, meta, x, r, t, acc);
    if (t == 0) {
        uint4 zv = *reinterpret_cast<const uint4*>(z + (size_t)r * 8);
        float zz[8] = {bflo(zv.x), bfhi(zv.x), bflo(zv.y), bfhi(zv.y),
                       bflo(zv.z), bfhi(zv.z), bflo(zv.w), bfhi(zv.w)};
        float val[5];
#pragma unroll
        for (int j = 0; j < 5; ++j) val[j] = acc[j] + zz[j] + bias[j];
        float mx = val[0];
#pragma unroll
        for (int j = 1; j < 5; ++j) mx = fmaxf(mx, val[j]);
        float s = 0.f;
#pragma unroll
        for (int j = 0; j < 5; ++j) s += expf(val[j] - mx);
        float l = logf(s);
#pragma unroll
        for (int j = 0; j < 5; ++j) out[(size_t)r * 5 + j] = val[j] - mx - l;
    }
}

// ---------------- MFMA GEMMs ----------------

// layer 1 projection: [u0|u1|u2] = xb @ Wc (128 x 192)
__global__ __launch_bounds__(256) void gemm_u(const u16* __restrict__ A,
                                              const u16* __restrict__ Wp,
                                              u16* __restrict__ u0, u16* __restrict__ u1,
                                              u16* __restrict__ u2, int n) {
    int wave = threadIdx.x >> 6;
    int lane = threadIdx.x & 63;
    int r0 = blockIdx.x * 64 + wave * 16;
    int row = r0 + (lane & 15);
    int rowc = row < n ? row : n - 1;
    int kofs = (lane >> 4) * 8;
    f32x4 acc[12] = {};
    for (int kt = 0; kt < 4; ++kt) {
        bf16x8 a = *reinterpret_cast<const bf16x8*>(A + (size_t)rowc * 128 + kt * 32 + kofs);
        const u16* wb = Wp + (size_t)kt * 12 * 512 + (size_t)lane * 8;
#pragma unroll
        for (int nt = 0; nt < 12; ++nt) {
            bf16x8 b = *reinterpret_cast<const bf16x8*>(wb + nt * 512);
            acc[nt] = __builtin_amdgcn_mfma_f32_16x16x32_bf16(a, b, acc[nt], 0, 0, 0);
        }
    }
    int col = lane & 15;
    u16* U[3] = {u0, u1, u2};
#pragma unroll
    for (int nt = 0; nt < 12; ++nt) {
        u16* dst = U[nt >> 2];
        int cc = (nt & 3) * 16 + col;
#pragma unroll
        for (int i = 0; i < 4; ++i) {
            int rr = r0 + (lane >> 4) * 4 + i;
            if (rr < n) dst[(size_t)rr * 64 + cc] = f2bf(acc[nt][i]);
        }
    }
}

// layer 2: out = relu([A0|A1|A2] @ W + bias), K=192
__global__ __launch_bounds__(256) void gemm3_mfma(const u16* __restrict__ A0,
                                                  const u16* __restrict__ A1,
                                                  const u16* __restrict__ A2,
                                                  const u16* __restrict__ Wp,
                                                  const float* __restrict__ bias,
                                                  u16* __restrict__ out, int n) {
    int wave = threadIdx.x >> 6;
    int lane = threadIdx.x & 63;
    int r0 = blockIdx.x * 64 + wave * 16;
    int row = r0 + (lane & 15);
    int rowc = row < n ? row : n - 1;
    int kofs = (lane >> 4) * 8;
    const u16* Ap[3] = {A0, A1, A2};
    f32x4 acc[4] = {};
    for (int kt = 0; kt < 6; ++kt) {
        const u16* Asrc = Ap[kt >> 1];
        int c0 = (kt & 1) * 32;
        bf16x8 a = *reinterpret_cast<const bf16x8*>(Asrc + (size_t)rowc * 64 + c0 + kofs);
        const u16* wb = Wp + (size_t)kt * 4 * 512 + (size_t)lane * 8;
#pragma unroll
        for (int nt = 0; nt < 4; ++nt) {
            bf16x8 b = *reinterpret_cast<const bf16x8*>(wb + nt * 512);
            acc[nt] = __builtin_amdgcn_mfma_f32_16x16x32_bf16(a, b, acc[nt], 0, 0, 0);
        }
    }
    int col = lane & 15;
#pragma unroll
    for (int nt = 0; nt < 4; ++nt) {
        float bb = bias[nt * 16 + col];
#pragma unroll
        for (int i = 0; i < 4; ++i) {
            int rr = r0 + (lane >> 4) * 4 + i;
            if (rr < n) {
                float v = fmaxf(acc[nt][i] + bb, 0.f);
                out[(size_t)rr * 64 + nt * 16 + col] = f2bf(v);
            }
        }
    }
}

// layer 3 projection: [p0|p1|p2](each N x 8) = h2 @ Wc3 (64 x 24)
__global__ __launch_bounds__(256) void gemm_proj(const u16* __restrict__ A,
                                                 const u16* __restrict__ Wp,
                                                 u16* __restrict__ p0, u16* __restrict__ p1,
                                                 u16* __restrict__ p2, int n) {
    int wave = threadIdx.x >> 6;
    int lane = threadIdx.x & 63;
    int r0 = blockIdx.x * 64 + wave * 16;
    int row = r0 + (lane & 15);
    int rowc = row < n ? row : n - 1;
    int kofs = (lane >> 4) * 8;
    f32x4 acc[2] = {};
    for (int kt = 0; kt < 2; ++kt) {
        bf16x8 a = *reinterpret_cast<const bf16x8*>(A + (size_t)rowc * 64 + kt * 32 + kofs);
        const u16* wb = Wp + (size_t)kt * 2 * 512 + (size_t)lane * 8;
#pragma unroll
        for (int nt = 0; nt < 2; ++nt) {
            bf16x8 b = *reinterpret_cast<const bf16x8*>(wb + nt * 512);
            acc[nt] = __builtin_amdgcn_mfma_f32_16x16x32_bf16(a, b, acc[nt], 0, 0, 0);
        }
    }
    int col = lane & 15;
    u16* P[3] = {p0, p1, p2};
#pragma unroll
    for (int nt = 0; nt < 2; ++nt) {
        int c = nt * 16 + col;
        if (c < 24) {
            u16* dst = P[c >> 3];
            int j = c & 7;
#pragma unroll
            for (int i = 0; i < 4; ++i) {
                int rr = r0 + (lane >> 4) * 4 + i;
                if (rr < n) dst[(size_t)rr * 8 + j] = f2bf(acc[nt][i]);
            }
        }
    }
}

// ---------------- launch ----------------

static inline size_t alignup(size_t v) { return (v + 255) & ~(size_t)255; }

extern "C" void kernel_launch(void* const* d_in, const int* in_sizes, int n_in,
                              void* d_out, int out_size, void* d_ws, size_t ws_size,
                              hipStream_t stream) {
    const float* x  = (const float*)d_in[0];
    const int*   ei = (const int*)d_in[1];
    const float* ew = (const float*)d_in[2];
    const float* W1 = (const float*)d_in[3];
    const float* b1 = (const float*)d_in[4];
    const float* W3 = (const float*)d_in[5];
    const float* b3 = (const float*)d_in[6];
    const float* W4 = (const float*)d_in[7];
    const float* b4 = (const float*)d_in[8];
    float* out = (float*)d_out;

    const int D = 128, H = 64;
    const int N = in_sizes[0] / D;
    const int E = in_sizes[2];
    const int* row = ei;
    const int* col = ei + E;

    char* ws = (char*)d_ws;
    size_t off = 0;
    auto alloc = [&](size_t bytes) { size_t o = off; off += alignup(bytes); return o; };

    float* dinv   = (float*)(ws + alloc((size_t)N * 4));
    int*   rowp   = (int*)  (ws + alloc((size_t)(N + 1) * 4));
    int*   bintot = (int*)  (ws + alloc(MAXB * 4));
    int*   bstart = (int*)  (ws + alloc((MAXB + 1) * 4));
    int*   P      = (int*)  (ws + alloc((size_t)MAXB * PB * 4));
    int2*  meta   = (int2*) (ws + alloc((size_t)E * 8));
    int2*  rec    = (int2*) (ws + alloc((size_t)E * 8));
    u16*   xb     = (u16*)  (ws + alloc((size_t)N * D * 2));
    u16*   A      = (u16*)  (ws + alloc((size_t)N * H * 2));
    u16*   B      = (u16*)  (ws + alloc((size_t)N * H * 2));
    u16*   C      = (u16*)  (ws + alloc((size_t)N * H * 2));
    u16*   Dd     = (u16*)  (ws + alloc((size_t)N * H * 2));
    u16*   P0     = (u16*)  (ws + alloc((size_t)N * 8 * 2));
    u16*   P1     = (u16*)  (ws + alloc((size_t)N * 8 * 2));
    u16*   P2     = (u16*)  (ws + alloc((size_t)N * 8 * 2));
    u16*   P3     = (u16*)  (ws + alloc((size_t)N * 8 * 2));
    u16*   Wpu    = (u16*)  (ws + alloc((size_t)4 * 12 * 512 * 2));
    u16*   Wp3    = (u16*)  (ws + alloc((size_t)6 * 4 * 512 * 2));
    u16*   Wpp    = (u16*)  (ws + alloc((size_t)2 * 2 * 512 * 2));

    const int NB = (N + 127) >> 7;        // coarse bins (<= MAXB)
    const int EB = (E + PB - 1) / PB;     // edges per partition block

    dim3 blk(256);
    int gN = (N + 255) / 256;

    // ---- CSR build (no global atomics) ----
    binA<<<PB, blk, 0, stream>>>(row, P, E, NB, EB);
    binB1<<<NB, blk, 0, stream>>>(P, bintot);
    binB2<<<1, blk, 0, stream>>>(bintot, bstart, NB);
    binC<<<PB, blk, 0, stream>>>(row, col, ew, P, bstart, rec, E, NB, EB);
    binD<<<NB, blk, 0, stream>>>(rec, bstart, meta, rowp, dinv, N, NB);
    scale_ev<<<gN, blk, 0, stream>>>(rowp, meta, dinv, N);

    // ---- prep (independent of CSR) ----
    int n2 = N * D / 2;
    to_bf16<<<(n2 + 255) / 256, blk, 0, stream>>>(x, (unsigned*)xb, n2);
    wpack_all<<<(4864 + 255) / 256, blk, 0, stream>>>(W1, W3, W4, Wpu, Wp3, Wpp);

    int g64 = (N + 31) / 32;
    int gG  = (N + 63) / 64;
    int g8  = (N + 63) / 64;

    // ---- layer 1: u=[u0|u1|u2]=x@Wc ; w=2*L*u2+u1 ; h1=relu(L*w+u0+b1) ----
    gemm_u<<<gG, blk, 0, stream>>>(xb, Wpu, A, B, C, N);                   // u0=A u1=B u2=C
    spmm64<1><<<g64, blk, 0, stream>>>(rowp, meta, C, B, nullptr, Dd, N);  // w -> Dd
    spmm64<3><<<g64, blk, 0, stream>>>(rowp, meta, Dd, A, b1, B, N);       // h1 -> B

    // ---- layer 2: Ty1=L*h1 ; Ty2=2*L*Ty1-h1 ; h2=relu([h1|Ty1|Ty2]@W3+b3) ----
    spmm64<0><<<g64, blk, 0, stream>>>(rowp, meta, B, nullptr, nullptr, C, N);  // Ty1 -> C
    spmm64<2><<<g64, blk, 0, stream>>>(rowp, meta, C, B, nullptr, A, N);        // Ty2 -> A
    gemm3_mfma<<<gG, blk, 0, stream>>>(B, C, A, Wp3, b3, Dd, N);                // h2 -> Dd

    // ---- layer 3: p=[p0|p1|p2]=h2@Wc3 ; w5=2*L*p2+p1 ; out=lsm(L*w5+p0+b4) ----
    gemm_proj<<<gG, blk, 0, stream>>>(Dd, Wpp, P0, P1, P2, N);
    spmm8_p2<<<g8, blk, 0, stream>>>(rowp, meta, P2, P1, P3, N);
    spmm8_lsm<<<g8, blk, 0, stream>>>(rowp, meta, P3, P0, b4, out, N);
}

// Round 7
// 306.338 us; speedup vs baseline: 3.0590x; 1.1327x over previous
//
#include <hip/hip_runtime.h>
#include <cstdint>
#include <cstddef>

typedef unsigned short u16;
typedef __attribute__((ext_vector_type(8))) short bf16x8;
typedef __attribute__((ext_vector_type(4))) float f32x4;

#define PB 1024   // partition blocks for binA/binC
#define MAXB 1024 // max coarse bins (N <= 131072)

// ---------------- bf16 helpers (RNE) ----------------
__device__ __forceinline__ float bflo(unsigned u) { return __uint_as_float(u << 16); }
__device__ __forceinline__ float bfhi(unsigned u) { return __uint_as_float(u & 0xFFFF0000u); }
__device__ __forceinline__ u16 f2bf(float f) {
    unsigned u = __float_as_uint(f);
    u += 0x7FFFu + ((u >> 16) & 1u);
    return (u16)(u >> 16);
}
__device__ __forceinline__ unsigned pack2(float a, float b) {
    return (unsigned)f2bf(a) | ((unsigned)f2bf(b) << 16);
}

// ================= CSR build: binned, zero global atomics =================

// pass A: per-block coarse-bin histogram (bin = row>>7)
__global__ __launch_bounds__(256) void binA(const int* __restrict__ row, int* __restrict__ P,
                                            int E, int NB, int EB) {
    __shared__ int hist[MAXB];
    int b = blockIdx.x;
    for (int i = threadIdx.x; i < NB; i += 256) hist[i] = 0;
    __syncthreads();
    int e0 = b * EB, e1 = min(E, e0 + EB);
    for (int e = e0 + threadIdx.x; e < e1; e += 256)
        atomicAdd(&hist[row[e] >> 7], 1);
    __syncthreads();
    for (int i = threadIdx.x; i < NB; i += 256) P[(size_t)i * PB + b] = hist[i];
}

// pass B1: per-bin exclusive scan over the PB=1024 block-partials; emit bin totals
__global__ __launch_bounds__(256) void binB1(int* __restrict__ P, int* __restrict__ bintot) {
    __shared__ int sh[256];
    int* p = P + (size_t)blockIdx.x * PB;
    int tid = threadIdx.x;
    int base = tid * 4;
    int v[4];
#pragma unroll
    for (int j = 0; j < 4; ++j) v[j] = p[base + j];
    int s = v[0] + v[1] + v[2] + v[3];
    sh[tid] = s;
    __syncthreads();
    for (int off = 1; off < 256; off <<= 1) {
        int t = (tid >= off) ? sh[tid - off] : 0;
        __syncthreads();
        sh[tid] += t;
        __syncthreads();
    }
    int run = sh[tid] - s;
#pragma unroll
    for (int j = 0; j < 4; ++j) { p[base + j] = run; run += v[j]; }
    if (tid == 255) bintot[blockIdx.x] = sh[255];
}

// pass B2: single-block exclusive scan over bin totals -> bstart[NB+1]
__global__ __launch_bounds__(256) void binB2(const int* __restrict__ bintot,
                                             int* __restrict__ bstart, int NB) {
    __shared__ int sh[256];
    int tid = threadIdx.x;
    int base = tid * 4;
    int v[4];
#pragma unroll
    for (int j = 0; j < 4; ++j) v[j] = (base + j < NB) ? bintot[base + j] : 0;
    int s = v[0] + v[1] + v[2] + v[3];
    sh[tid] = s;
    __syncthreads();
    for (int off = 1; off < 256; off <<= 1) {
        int t = (tid >= off) ? sh[tid - off] : 0;
        __syncthreads();
        sh[tid] += t;
        __syncthreads();
    }
    int run = sh[tid] - s;
#pragma unroll
    for (int j = 0; j < 4; ++j) {
        if (base + j < NB) bstart[base + j] = run;
        run += v[j];
    }
    if (tid == 255) bstart[NB] = sh[255];
}

// pass C: scatter edges into bin-contiguous records {col | rowlo<<17, w}
__global__ __launch_bounds__(256) void binC(const int* __restrict__ row, const int* __restrict__ col,
                                            const float* __restrict__ w, const int* __restrict__ P,
                                            const int* __restrict__ bstart, int2* __restrict__ rec,
                                            int E, int NB, int EB) {
    __shared__ int cur[MAXB];
    int b = blockIdx.x;
    for (int i = threadIdx.x; i < NB; i += 256)
        cur[i] = bstart[i] + P[(size_t)i * PB + b];
    __syncthreads();
    int e0 = b * EB, e1 = min(E, e0 + EB);
    for (int e = e0 + threadIdx.x; e < e1; e += 256) {
        int r = row[e];
        int bin = r >> 7;
        int slot = atomicAdd(&cur[bin], 1);
        rec[slot] = make_int2(col[e] | ((r & 127) << 17), __float_as_int(w[e]));
    }
}

// pass D: per-bin fine CSR: rowp, dinv, and final meta placement
__global__ __launch_bounds__(256) void binD(const int2* __restrict__ rec,
                                            const int* __restrict__ bstart,
                                            int2* __restrict__ meta, int* __restrict__ rowp,
                                            float* __restrict__ dinv, int N, int NB) {
    __shared__ int cnt[128], st[128], cur[128];
    __shared__ float deg[128];
    int bin = blockIdx.x;
    int tid = threadIdx.x;
    if (tid < 128) { cnt[tid] = 0; deg[tid] = 0.f; }
    __syncthreads();
    int e0 = bstart[bin], e1 = bstart[bin + 1];
    for (int e = e0 + tid; e < e1; e += 256) {
        int2 v = rec[e];
        int rl = (v.x >> 17) & 127;
        atomicAdd(&cnt[rl], 1);
        atomicAdd(&deg[rl], __int_as_float(v.y));
    }
    __syncthreads();
    if (tid < 128) st[tid] = cnt[tid];
    __syncthreads();
    for (int off = 1; off < 128; off <<= 1) {
        int t = (tid >= off && tid < 128) ? st[tid - off] : 0;
        __syncthreads();
        if (tid < 128) st[tid] += t;
        __syncthreads();
    }
    int rows = min(128, N - bin * 128);
    if (tid < 128) {
        int excl = st[tid] - cnt[tid];
        cur[tid] = e0 + excl;
        if (tid < rows) {
            rowp[bin * 128 + tid] = e0 + excl;
            float d = deg[tid];
            dinv[bin * 128 + tid] = d > 0.f ? rsqrtf(d) : 0.f;
        }
    }
    if (bin == NB - 1 && tid == 0) rowp[N] = e1;
    __syncthreads();
    for (int e = e0 + tid; e < e1; e += 256) {
        int2 v = rec[e];
        int rl = (v.x >> 17) & 127;
        int slot = atomicAdd(&cur[rl], 1);
        meta[slot] = make_int2(v.x & 0x1FFFF, v.y);
    }
}

// per-row: ev[e] = -dinv[r] * w * dinv[col[e]] in place (unrolled x4 for MLP)
__global__ void scale_ev(const int* __restrict__ rowp, int2* __restrict__ meta,
                         const float* __restrict__ dinv, int n) {
    int r = blockIdx.x * blockDim.x + threadIdx.x;
    if (r >= n) return;
    int e0 = rowp[r], e1 = rowp[r + 1];
    float dr = dinv[r];
    int e = e0;
    for (; e + 4 <= e1; e += 4) {
        int2 v0 = meta[e], v1 = meta[e + 1], v2 = meta[e + 2], v3 = meta[e + 3];
        float d0 = dinv[v0.x], d1 = dinv[v1.x], d2 = dinv[v2.x], d3 = dinv[v3.x];
        v0.y = __float_as_int(-dr * __int_as_float(v0.y) * d0);
        v1.y = __float_as_int(-dr * __int_as_float(v1.y) * d1);
        v2.y = __float_as_int(-dr * __int_as_float(v2.y) * d2);
        v3.y = __float_as_int(-dr * __int_as_float(v3.y) * d3);
        meta[e] = v0; meta[e + 1] = v1; meta[e + 2] = v2; meta[e + 3] = v3;
    }
    for (; e < e1; ++e) {
        int2 v = meta[e];
        v.y = __float_as_int(-dr * __int_as_float(v.y) * dinv[v.x]);
        meta[e] = v;
    }
}

// ---------------- fp32 -> bf16 bulk convert ----------------
__global__ void to_bf16(const float* __restrict__ in, unsigned* __restrict__ out, int n2) {
    int i = blockIdx.x * blockDim.x + threadIdx.x;  // 2 floats per thread
    if (i < n2) {
        float2 v = reinterpret_cast<const float2*>(in)[i];
        out[i] = pack2(v.x, v.y);
    }
}

// ---------------- W packs into MFMA B-fragment layout (fused) ----------------
__global__ void wpack_all(const float* __restrict__ W1, const float* __restrict__ W3,
                          const float* __restrict__ W4, u16* __restrict__ Wpu,
                          u16* __restrict__ Wp3, u16* __restrict__ Wpp) {
    int gi = blockIdx.x * blockDim.x + threadIdx.x;
    if (gi < 3072) {
        int idx = gi;
        int lane = idx & 63;
        int nt = (idx >> 6) % 12;
        int kt = idx / 768;
        int krow = kt * 32 + (lane >> 4) * 8;
        int c = nt * 16 + (lane & 15);
        u16 tmp[8];
#pragma unroll
        for (int j = 0; j < 8; ++j) {
            int k = krow + j;
            float v;
            if (c < 64)       v = W1[(size_t)k * 64 + c] - W1[2 * 8192 + (size_t)k * 64 + c];
            else if (c < 128) v = W1[8192 + (size_t)k * 64 + (c - 64)];
            else              v = W1[2 * 8192 + (size_t)k * 64 + (c - 128)];
            tmp[j] = f2bf(v);
        }
        *reinterpret_cast<uint4*>(Wpu + (size_t)idx * 8) = *reinterpret_cast<const uint4*>(tmp);
    } else if (gi < 3072 + 1536) {
        int idx = gi - 3072;
        int lane = idx & 63;
        int nt = (idx >> 6) & 3;
        int kt = idx >> 8;
        int krow = kt * 32 + (lane >> 4) * 8;
        int c = nt * 16 + (lane & 15);
        u16 tmp[8];
#pragma unroll
        for (int j = 0; j < 8; ++j) tmp[j] = f2bf(W3[(size_t)(krow + j) * 64 + c]);
        *reinterpret_cast<uint4*>(Wp3 + (size_t)idx * 8) = *reinterpret_cast<const uint4*>(tmp);
    } else if (gi < 3072 + 1536 + 256) {
        int idx = gi - (3072 + 1536);
        int lane = idx & 63;
        int nt = (idx >> 6) & 1;
        int kt = idx >> 7;
        int krow = kt * 32 + (lane >> 4) * 8;
        int c = nt * 16 + (lane & 15);
        u16 tmp[8];
#pragma unroll
        for (int j = 0; j < 8; ++j) {
            int k = krow + j;
            float v = 0.f;
            if (c < 5)                  v = W4[(size_t)k * 5 + c] - W4[640 + (size_t)k * 5 + c];
            else if (c >= 8 && c < 13)  v = W4[320 + (size_t)k * 5 + (c - 8)];
            else if (c >= 16 && c < 21) v = W4[640 + (size_t)k * 5 + (c - 16)];
            tmp[j] = f2bf(v);
        }
        *reinterpret_cast<uint4*>(Wpp + (size_t)idx * 8) = *reinterpret_cast<const uint4*>(tmp);
    }
}

// ---------------- SpMM (CSR) F=64, bf16, fp32 accumulate ----------------
// MODE 0: y = acc ; 1: y = 2*acc + z ; 2: y = 2*acc - z ; 3: y = relu(acc + z + bias)
template <int MODE>
__global__ __launch_bounds__(256) void spmm64(const int* __restrict__ rp,
                                              const int2* __restrict__ meta,
                                              const u16* __restrict__ x,
                                              const u16* __restrict__ z,
                                              const float* __restrict__ bias,
                                              u16* __restrict__ y, int n) {
    int r = blockIdx.x * 32 + (threadIdx.x >> 3);
    if (r >= n) return;
    int f = (threadIdx.x & 7) * 8;
    int e0 = rp[r], e1 = rp[r + 1];
    float acc[8] = {0.f, 0.f, 0.f, 0.f, 0.f, 0.f, 0.f, 0.f};
    auto fma8 = [&](uint4 xv, float w) {
        acc[0] += w * bflo(xv.x); acc[1] += w * bfhi(xv.x);
        acc[2] += w * bflo(xv.y); acc[3] += w * bfhi(xv.y);
        acc[4] += w * bflo(xv.z); acc[5] += w * bfhi(xv.z);
        acc[6] += w * bflo(xv.w); acc[7] += w * bfhi(xv.w);
    };
    int e = e0;
    // unrolled x4: 4 independent gathers in flight per iteration (latency hiding)
    for (; e + 4 <= e1; e += 4) {
        int2 m0 = meta[e], m1 = meta[e + 1], m2 = meta[e + 2], m3 = meta[e + 3];
        uint4 v0 = *reinterpret_cast<const uint4*>(x + (size_t)m0.x * 64 + f);
        uint4 v1 = *reinterpret_cast<const uint4*>(x + (size_t)m1.x * 64 + f);
        uint4 v2 = *reinterpret_cast<const uint4*>(x + (size_t)m2.x * 64 + f);
        uint4 v3 = *reinterpret_cast<const uint4*>(x + (size_t)m3.x * 64 + f);
        fma8(v0, __int_as_float(m0.y));
        fma8(v1, __int_as_float(m1.y));
        fma8(v2, __int_as_float(m2.y));
        fma8(v3, __int_as_float(m3.y));
    }
    for (; e < e1; ++e) {
        int2 m = meta[e];
        uint4 xv = *reinterpret_cast<const uint4*>(x + (size_t)m.x * 64 + f);
        fma8(xv, __int_as_float(m.y));
    }
    if (MODE == 1 || MODE == 2) {
        uint4 zv = *reinterpret_cast<const uint4*>(z + (size_t)r * 64 + f);
        float zz[8] = {bflo(zv.x), bfhi(zv.x), bflo(zv.y), bfhi(zv.y),
                       bflo(zv.z), bfhi(zv.z), bflo(zv.w), bfhi(zv.w)};
#pragma unroll
        for (int j = 0; j < 8; ++j)
            acc[j] = (MODE == 1) ? 2.f * acc[j] + zz[j] : 2.f * acc[j] - zz[j];
    } else if (MODE == 3) {
        uint4 zv = *reinterpret_cast<const uint4*>(z + (size_t)r * 64 + f);
        float zz[8] = {bflo(zv.x), bfhi(zv.x), bflo(zv.y), bfhi(zv.y),
                       bflo(zv.z), bfhi(zv.z), bflo(zv.w), bfhi(zv.w)};
        float4 bl = *reinterpret_cast<const float4*>(bias + f);
        float4 bh = *reinterpret_cast<const float4*>(bias + f + 4);
        float bb[8] = {bl.x, bl.y, bl.z, bl.w, bh.x, bh.y, bh.z, bh.w};
#pragma unroll
        for (int j = 0; j < 8; ++j) acc[j] = fmaxf(acc[j] + zz[j] + bb[j], 0.f);
    }
    uint4 o;
    o.x = pack2(acc[0], acc[1]);
    o.y = pack2(acc[2], acc[3]);
    o.z = pack2(acc[4], acc[5]);
    o.w = pack2(acc[6], acc[7]);
    *reinterpret_cast<uint4*>(y + (size_t)r * 64 + f) = o;
}

// ---------------- SpMM width-8 (padded 5), 4 threads per row ----------------
__device__ __forceinline__ void spmm8_acc(const int* rp, const int2* meta, const u16* x,
                                          int r, int t, float* acc) {
    int e0 = rp[r], e1 = rp[r + 1];
    auto fma8 = [&](uint4 xv, float w) {
        acc[0] += w * bflo(xv.x); acc[1] += w * bfhi(xv.x);
        acc[2] += w * bflo(xv.y); acc[3] += w * bfhi(xv.y);
        acc[4] += w * bflo(xv.z); acc[5] += w * bfhi(xv.z);
        acc[6] += w * bflo(xv.w); acc[7] += w * bfhi(xv.w);
    };
    int e = e0 + t;
    for (; e + 4 < e1; e += 8) {
        int2 m0 = meta[e], m1 = meta[e + 4];
        uint4 v0 = *reinterpret_cast<const uint4*>(x + (size_t)m0.x * 8);
        uint4 v1 = *reinterpret_cast<const uint4*>(x + (size_t)m1.x * 8);
        fma8(v0, __int_as_float(m0.y));
        fma8(v1, __int_as_float(m1.y));
    }
    for (; e < e1; e += 4) {
        int2 m = meta[e];
        uint4 xv = *reinterpret_cast<const uint4*>(x + (size_t)m.x * 8);
        fma8(xv, __int_as_float(m.y));
    }
#pragma unroll
    for (int j = 0; j < 8; ++j) acc[j] += __shfl_xor(acc[j], 1);
#pragma unroll
    for (int j = 0; j < 8; ++j) acc[j] += __shfl_xor(acc[j], 2);
}

// w5 = 2*L*p2 + p1
__global__ __launch_bounds__(256) void spmm8_p2(const int* __restrict__ rp,
                                                const int2* __restrict__ meta,
                                                const u16* __restrict__ x,
                                                const u16* __restrict__ z,
                                                u16* __restrict__ y, int n) {
    int r = blockIdx.x * 64 + (threadIdx.x >> 2);
    if (r >= n) return;
    int t = threadIdx.x & 3;
    float acc[8] = {0.f, 0.f, 0.f, 0.f, 0.f, 0.f, 0.f, 0.f};
    spmm8_acc(rp, meta, x, r, t, acc);
    if (t == 0) {
        uint4 zv = *reinterpret_cast<const uint4*>(z + (size_t)r * 8);
        float zz[8] = {bflo(zv.x), bfhi(zv.x), bflo(zv.y), bfhi(zv.y),
                       bflo(zv.z), bfhi(zv.z), bflo(zv.w), bfhi(zv.w)};
        uint4 o;
        o.x = pack2(2.f * acc[0] + zz[0], 2.f * acc[1] + zz[1]);
        o.y = pack2(2.f * acc[2] + zz[2], 2.f * acc[3] + zz[3]);
        o.z = pack2(2.f * acc[4] + zz[4], 2.f * acc[5] + zz[5]);
        o.w = pack2(2.f * acc[6] + zz[6], 2.f * acc[7] + zz[7]);
        *reinterpret_cast<uint4*>(y + (size_t)r * 8) = o;
    }
}

// out = log_softmax(L*w5 + p0 + b4) over 5 classes, fp32 out
__global__ __launch_bounds__(256) void spmm8_lsm(const int* __restrict__ rp,
                                                 const int2* __restrict__ meta,
                                                 const u16* __restrict__ x,
                                                 const u16* __restrict__ z,
                                                 const float* __restrict__ bias,
                                                 float* __restrict__ out, int n) {
    int r = blockIdx.x * 64 + (threadIdx.x >> 2);
    if (r >= n) return;
    int t = threadIdx.x & 3;
    float acc[8] = {0.f, 0.f, 0.f, 0.f, 0.f, 0.f, 0.f, 0.f};
    spmm8_acc(rp, meta, x, r, t, acc);
    if (t == 0) {
        uint4 zv = *reinterpret_cast<const uint4*>(z + (size_t)r * 8);
        float zz[8] = {bflo(zv.x), bfhi(zv.x), bflo(zv.y), bfhi(zv.y),
                       bflo(zv.z), bfhi(zv.z), bflo(zv.w), bfhi(zv.w)};
        float val[5];
#pragma unroll
        for (int j = 0; j < 5; ++j) val[j] = acc[j] + zz[j] + bias[j];
        float mx = val[0];
#pragma unroll
        for (int j = 1; j < 5; ++j) mx = fmaxf(mx, val[j]);
        float s = 0.f;
#pragma unroll
        for (int j = 0; j < 5; ++j) s += expf(val[j] - mx);
        float l = logf(s);
#pragma unroll
        for (int j = 0; j < 5; ++j) out[(size_t)r * 5 + j] = val[j] - mx - l;
    }
}

// ---------------- MFMA GEMMs ----------------

// layer 1 projection: [u0|u1|u2] = xb @ Wc (128 x 192)
__global__ __launch_bounds__(256) void gemm_u(const u16* __restrict__ A,
                                              const u16* __restrict__ Wp,
                                              u16* __restrict__ u0, u16* __restrict__ u1,
                                              u16* __restrict__ u2, int n) {
    int wave = threadIdx.x >> 6;
    int lane = threadIdx.x & 63;
    int r0 = blockIdx.x * 64 + wave * 16;
    int row = r0 + (lane & 15);
    int rowc = row < n ? row : n - 1;
    int kofs = (lane >> 4) * 8;
    f32x4 acc[12] = {};
    for (int kt = 0; kt < 4; ++kt) {
        bf16x8 a = *reinterpret_cast<const bf16x8*>(A + (size_t)rowc * 128 + kt * 32 + kofs);
        const u16* wb = Wp + (size_t)kt * 12 * 512 + (size_t)lane * 8;
#pragma unroll
        for (int nt = 0; nt < 12; ++nt) {
            bf16x8 b = *reinterpret_cast<const bf16x8*>(wb + nt * 512);
            acc[nt] = __builtin_amdgcn_mfma_f32_16x16x32_bf16(a, b, acc[nt], 0, 0, 0);
        }
    }
    int col = lane & 15;
    u16* U[3] = {u0, u1, u2};
#pragma unroll
    for (int nt = 0; nt < 12; ++nt) {
        u16* dst = U[nt >> 2];
        int cc = (nt & 3) * 16 + col;
#pragma unroll
        for (int i = 0; i < 4; ++i) {
            int rr = r0 + (lane >> 4) * 4 + i;
            if (rr < n) dst[(size_t)rr * 64 + cc] = f2bf(acc[nt][i]);
        }
    }
}

// layer 2: out = relu([A0|A1|A2] @ W + bias), K=192
__global__ __launch_bounds__(256) void gemm3_mfma(const u16* __restrict__ A0,
                                                  const u16* __restrict__ A1,
                                                  const u16* __restrict__ A2,
                                                  const u16* __restrict__ Wp,
                                                  const float* __restrict__ bias,
                                                  u16* __restrict__ out, int n) {
    int wave = threadIdx.x >> 6;
    int lane = threadIdx.x & 63;
    int r0 = blockIdx.x * 64 + wave * 16;
    int row = r0 + (lane & 15);
    int rowc = row < n ? row : n - 1;
    int kofs = (lane >> 4) * 8;
    const u16* Ap[3] = {A0, A1, A2};
    f32x4 acc[4] = {};
    for (int kt = 0; kt < 6; ++kt) {
        const u16* Asrc = Ap[kt >> 1];
        int c0 = (kt & 1) * 32;
        bf16x8 a = *reinterpret_cast<const bf16x8*>(Asrc + (size_t)rowc * 64 + c0 + kofs);
        const u16* wb = Wp + (size_t)kt * 4 * 512 + (size_t)lane * 8;
#pragma unroll
        for (int nt = 0; nt < 4; ++nt) {
            bf16x8 b = *reinterpret_cast<const bf16x8*>(wb + nt * 512);
            acc[nt] = __builtin_amdgcn_mfma_f32_16x16x32_bf16(a, b, acc[nt], 0, 0, 0);
        }
    }
    int col = lane & 15;
#pragma unroll
    for (int nt = 0; nt < 4; ++nt) {
        float bb = bias[nt * 16 + col];
#pragma unroll
        for (int i = 0; i < 4; ++i) {
            int rr = r0 + (lane >> 4) * 4 + i;
            if (rr < n) {
                float v = fmaxf(acc[nt][i] + bb, 0.f);
                out[(size_t)rr * 64 + nt * 16 + col] = f2bf(v);
            }
        }
    }
}

// layer 3 projection: [p0|p1|p2](each N x 8) = h2 @ Wc3 (64 x 24)
__global__ __launch_bounds__(256) void gemm_proj(const u16* __restrict__ A,
                                                 const u16* __restrict__ Wp,
                                                 u16* __restrict__ p0, u16* __restrict__ p1,
                                                 u16* __restrict__ p2, int n) {
    int wave = threadIdx.x >> 6;
    int lane = threadIdx.x & 63;
    int r0 = blockIdx.x * 64 + wave * 16;
    int row = r0 + (lane & 15);
    int rowc = row < n ? row : n - 1;
    int kofs = (lane >> 4) * 8;
    f32x4 acc[2] = {};
    for (int kt = 0; kt < 2; ++kt) {
        bf16x8 a = *reinterpret_cast<const bf16x8*>(A + (size_t)rowc * 64 + kt * 32 + kofs);
        const u16* wb = Wp + (size_t)kt * 2 * 512 + (size_t)lane * 8;
#pragma unroll
        for (int nt = 0; nt < 2; ++nt) {
            bf16x8 b = *reinterpret_cast<const bf16x8*>(wb + nt * 512);
            acc[nt] = __builtin_amdgcn_mfma_f32_16x16x32_bf16(a, b, acc[nt], 0, 0, 0);
        }
    }
    int col = lane & 15;
    u16* P[3] = {p0, p1, p2};
#pragma unroll
    for (int nt = 0; nt < 2; ++nt) {
        int c = nt * 16 + col;
        if (c < 24) {
            u16* dst = P[c >> 3];
            int j = c & 7;
#pragma unroll
            for (int i = 0; i < 4; ++i) {
                int rr = r0 + (lane >> 4) * 4 + i;
                if (rr < n) dst[(size_t)rr * 8 + j] = f2bf(acc[nt][i]);
            }
        }
    }
}

// ---------------- launch ----------------

static inline size_t alignup(size_t v) { return (v + 255) & ~(size_t)255; }

extern "C" void kernel_launch(void* const* d_in, const int* in_sizes, int n_in,
                              void* d_out, int out_size, void* d_ws, size_t ws_size,
                              hipStream_t stream) {
    const float* x  = (const float*)d_in[0];
    const int*   ei = (const int*)d_in[1];
    const float* ew = (const float*)d_in[2];
    const float* W1 = (const float*)d_in[3];
    const float* b1 = (const float*)d_in[4];
    const float* W3 = (const float*)d_in[5];
    const float* b3 = (const float*)d_in[6];
    const float* W4 = (const float*)d_in[7];
    const float* b4 = (const float*)d_in[8];
    float* out = (float*)d_out;

    const int D = 128, H = 64;
    const int N = in_sizes[0] / D;
    const int E = in_sizes[2];
    const int* row = ei;
    const int* col = ei + E;

    char* ws = (char*)d_ws;
    size_t off = 0;
    auto alloc = [&](size_t bytes) { size_t o = off; off += alignup(bytes); return o; };

    float* dinv   = (float*)(ws + alloc((size_t)N * 4));
    int*   rowp   = (int*)  (ws + alloc((size_t)(N + 1) * 4));
    int*   bintot = (int*)  (ws + alloc(MAXB * 4));
    int*   bstart = (int*)  (ws + alloc((MAXB + 1) * 4));
    int*   P      = (int*)  (ws + alloc((size_t)MAXB * PB * 4));
    int2*  meta   = (int2*) (ws + alloc((size_t)E * 8));
    int2*  rec    = (int2*) (ws + alloc((size_t)E * 8));
    u16*   xb     = (u16*)  (ws + alloc((size_t)N * D * 2));
    u16*   A      = (u16*)  (ws + alloc((size_t)N * H * 2));
    u16*   B      = (u16*)  (ws + alloc((size_t)N * H * 2));
    u16*   C      = (u16*)  (ws + alloc((size_t)N * H * 2));
    u16*   Dd     = (u16*)  (ws + alloc((size_t)N * H * 2));
    u16*   P0     = (u16*)  (ws + alloc((size_t)N * 8 * 2));
    u16*   P1     = (u16*)  (ws + alloc((size_t)N * 8 * 2));
    u16*   P2     = (u16*)  (ws + alloc((size_t)N * 8 * 2));
    u16*   P3     = (u16*)  (ws + alloc((size_t)N * 8 * 2));
    u16*   Wpu    = (u16*)  (ws + alloc((size_t)4 * 12 * 512 * 2));
    u16*   Wp3    = (u16*)  (ws + alloc((size_t)6 * 4 * 512 * 2));
    u16*   Wpp    = (u16*)  (ws + alloc((size_t)2 * 2 * 512 * 2));

    const int NB = (N + 127) >> 7;        // coarse bins (<= MAXB)
    const int EB = (E + PB - 1) / PB;     // edges per partition block

    dim3 blk(256);
    int gN = (N + 255) / 256;

    // ---- CSR build (no global atomics) ----
    binA<<<PB, blk, 0, stream>>>(row, P, E, NB, EB);
    binB1<<<NB, blk, 0, stream>>>(P, bintot);
    binB2<<<1, blk, 0, stream>>>(bintot, bstart, NB);
    binC<<<PB, blk, 0, stream>>>(row, col, ew, P, bstart, rec, E, NB, EB);
    binD<<<NB, blk, 0, stream>>>(rec, bstart, meta, rowp, dinv, N, NB);
    scale_ev<<<gN, blk, 0, stream>>>(rowp, meta, dinv, N);

    // ---- prep (independent of CSR) ----
    int n2 = N * D / 2;
    to_bf16<<<(n2 + 255) / 256, blk, 0, stream>>>(x, (unsigned*)xb, n2);
    wpack_all<<<(4864 + 255) / 256, blk, 0, stream>>>(W1, W3, W4, Wpu, Wp3, Wpp);

    int g64 = (N + 31) / 32;
    int gG  = (N + 63) / 64;
    int g8  = (N + 63) / 64;

    // ---- layer 1: u=[u0|u1|u2]=x@Wc ; w=2*L*u2+u1 ; h1=relu(L*w+u0+b1) ----
    gemm_u<<<gG, blk, 0, stream>>>(xb, Wpu, A, B, C, N);                   // u0=A u1=B u2=C
    spmm64<1><<<g64, blk, 0, stream>>>(rowp, meta, C, B, nullptr, Dd, N);  // w -> Dd
    spmm64<3><<<g64, blk, 0, stream>>>(rowp, meta, Dd, A, b1, B, N);       // h1 -> B

    // ---- layer 2: Ty1=L*h1 ; Ty2=2*L*Ty1-h1 ; h2=relu([h1|Ty1|Ty2]@W3+b3) ----
    spmm64<0><<<g64, blk, 0, stream>>>(rowp, meta, B, nullptr, nullptr, C, N);  // Ty1 -> C
    spmm64<2><<<g64, blk, 0, stream>>>(rowp, meta, C, B, nullptr, A, N);        // Ty2 -> A
    gemm3_mfma<<<gG, blk, 0, stream>>>(B, C, A, Wp3, b3, Dd, N);                // h2 -> Dd

    // ---- layer 3: p=[p0|p1|p2]=h2@Wc3 ; w5=2*L*p2+p1 ; out=lsm(L*w5+p0+b4) ----
    gemm_proj<<<gG, blk, 0, stream>>>(Dd, Wpp, P0, P1, P2, N);
    spmm8_p2<<<g8, blk, 0, stream>>>(rowp, meta, P2, P1, P3, N);
    spmm8_lsm<<<g8, blk, 0, stream>>>(rowp, meta, P3, P0, b4, out, N);
}